// Round 1
// baseline (2136.097 us; speedup 1.0000x reference)
//
#include <hip/hip_runtime.h>
#include <math.h>

constexpr int NN = 100000;
constexpr int EE = 1600000;
constexpr int IND = 256;
constexpr int F1 = 32;
constexpr int HF = 128;   // H*F1
constexpr int C  = 40;
constexpr float SLOPE = 0.2f;

// ---------------- GEMM1: h1 = feat @ W1  (N x 256) @ (256 x 128) ----------------
__global__ __launch_bounds__(256) void k_gemm1(const float* __restrict__ feat,
                                               const float* __restrict__ W1,
                                               float* __restrict__ h1) {
    __shared__ float a_s[32][33];
    __shared__ float b_s[32][128];
    const int tid = threadIdx.x;
    const int tx = tid & 31, ty = tid >> 5;
    const int n0 = blockIdx.x * 32;
    float4 acc[4] = {};
    for (int kt = 0; kt < IND; kt += 32) {
        { // stage A tile 32x32
            int r = tid >> 3, c4 = (tid & 7) * 4;
            const float4 v = *(const float4*)&feat[(size_t)(n0 + r) * IND + kt + c4];
            a_s[r][c4] = v.x; a_s[r][c4 + 1] = v.y; a_s[r][c4 + 2] = v.z; a_s[r][c4 + 3] = v.w;
        }
        { // stage B tile 32x128
            int cc = tx * 4;
            #pragma unroll
            for (int rep = 0; rep < 4; ++rep) {
                int kr = ty + rep * 8;
                *(float4*)&b_s[kr][cc] = *(const float4*)&W1[(size_t)(kt + kr) * HF + cc];
            }
        }
        __syncthreads();
        #pragma unroll
        for (int k = 0; k < 32; ++k) {
            float4 b4 = *(float4*)&b_s[k][tx * 4];
            #pragma unroll
            for (int i = 0; i < 4; ++i) {
                float a = a_s[ty * 4 + i][k];
                acc[i].x += a * b4.x; acc[i].y += a * b4.y;
                acc[i].z += a * b4.z; acc[i].w += a * b4.w;
            }
        }
        __syncthreads();
    }
    #pragma unroll
    for (int i = 0; i < 4; ++i)
        *(float4*)&h1[(size_t)(n0 + ty * 4 + i) * HF + tx * 4] = acc[i];
}

// ---------------- el1/er1: per-node attention halves ----------------
__global__ __launch_bounds__(256) void k_elr1(const float* __restrict__ h1,
                                              const float* __restrict__ al1,
                                              const float* __restrict__ ar1,
                                              float* __restrict__ el1,
                                              float* __restrict__ er1) {
    const int wid = threadIdx.x >> 6, lane = threadIdx.x & 63;
    const int n = blockIdx.x * 4 + wid;
    const int head = lane >> 4;              // col = 2*lane, head = col/32
    const int fo = (lane & 15) * 2;          // feature offset within head
    float2 h = *(const float2*)&h1[(size_t)n * HF + lane * 2];
    float2 al = *(const float2*)&al1[head * F1 + fo];
    float2 ar = *(const float2*)&ar1[head * F1 + fo];
    float pel = h.x * al.x + h.y * al.y;
    float per = h.x * ar.x + h.y * ar.y;
    #pragma unroll
    for (int m = 1; m < 16; m <<= 1) {
        pel += __shfl_xor(pel, m, 64);
        per += __shfl_xor(per, m, 64);
    }
    if ((lane & 15) == 0) {
        el1[n * 4 + head] = pel;
        er1[n * 4 + head] = per;
    }
}

// ---------------- layer-1 edge aggregation (one wave per edge) ----------------
__global__ __launch_bounds__(256) void k_edge1(const int* __restrict__ src,
                                               const int* __restrict__ dst,
                                               const float* __restrict__ h1,
                                               const float* __restrict__ el1,
                                               const float* __restrict__ er1,
                                               float* __restrict__ acc1,
                                               float* __restrict__ ssum1) {
    const int wid = threadIdx.x >> 6, lane = threadIdx.x & 63;
    const int e = blockIdx.x * 4 + wid;
    if (e >= EE) return;
    const int s = src[e], d = dst[e];
    const int head = lane >> 4;
    float sc = el1[s * 4 + head] + er1[d * 4 + head];
    sc = sc > 0.f ? sc : SLOPE * sc;
    const float ee = __expf(sc);
    float2 h = *(const float2*)&h1[(size_t)s * HF + lane * 2];
    atomicAdd(&acc1[(size_t)d * HF + lane * 2],     ee * h.x);
    atomicAdd(&acc1[(size_t)d * HF + lane * 2 + 1], ee * h.y);
    if ((lane & 15) == 0) atomicAdd(&ssum1[d * 4 + head], ee);
}

// ---------------- normalize + bias + ELU -> x ----------------
__global__ __launch_bounds__(256) void k_norm_elu(const float* __restrict__ acc1,
                                                  const float* __restrict__ ssum1,
                                                  const float* __restrict__ b1,
                                                  float* __restrict__ x) {
    const int idx = blockIdx.x * 256 + threadIdx.x;  // one float4 each, N*32 total
    const int n = idx >> 5, q = idx & 31;
    if (n >= NN) return;
    float ss = ssum1[n * 4 + (q >> 3)];
    float inv = ss > 0.f ? 1.f / ss : 0.f;
    float4 a = *(const float4*)&acc1[(size_t)n * HF + q * 4];
    float4 b = *(const float4*)&b1[q * 4];
    float4 r;
    r.x = a.x * inv + b.x; r.y = a.y * inv + b.y;
    r.z = a.z * inv + b.z; r.w = a.w * inv + b.w;
    r.x = r.x > 0.f ? r.x : expm1f(r.x);
    r.y = r.y > 0.f ? r.y : expm1f(r.y);
    r.z = r.z > 0.f ? r.z : expm1f(r.z);
    r.w = r.w > 0.f ? r.w : expm1f(r.w);
    *(float4*)&x[(size_t)n * HF + q * 4] = r;
}

// ---------------- GEMM2 + el2/er2 (one wave per node) ----------------
__global__ __launch_bounds__(256) void k_gemm2(const float* __restrict__ x,
                                               const float* __restrict__ W2,
                                               const float* __restrict__ al2,
                                               const float* __restrict__ ar2,
                                               float* __restrict__ h2,
                                               float* __restrict__ el2,
                                               float* __restrict__ er2) {
    __shared__ float w2s[HF * C];
    __shared__ float xs[4][HF];
    __shared__ float al2s[C], ar2s[C];
    const int tid = threadIdx.x;
    for (int i = tid; i < HF * C; i += 256) w2s[i] = W2[i];
    if (tid < C) { al2s[tid] = al2[tid]; ar2s[tid] = ar2[tid]; }
    const int wid = tid >> 6, lane = tid & 63;
    const int n = blockIdx.x * 4 + wid;
    xs[wid][lane] = x[(size_t)n * HF + lane];
    xs[wid][lane + 64] = x[(size_t)n * HF + lane + 64];
    __syncthreads();
    float acc = 0.f;
    if (lane < C) {
        #pragma unroll 4
        for (int k = 0; k < HF; ++k) acc += xs[wid][k] * w2s[k * C + lane];
    }
    float pel = lane < C ? acc * al2s[lane] : 0.f;
    float per = lane < C ? acc * ar2s[lane] : 0.f;
    #pragma unroll
    for (int m = 1; m < 64; m <<= 1) {
        pel += __shfl_xor(pel, m, 64);
        per += __shfl_xor(per, m, 64);
    }
    if (lane < C) h2[(size_t)n * C + lane] = acc;
    if (lane == 0) { el2[n] = pel; er2[n] = per; }
}

// ---------------- layer-2 edge aggregation ----------------
__global__ __launch_bounds__(256) void k_edge2(const int* __restrict__ src,
                                               const int* __restrict__ dst,
                                               const float* __restrict__ h2,
                                               const float* __restrict__ el2,
                                               const float* __restrict__ er2,
                                               float* __restrict__ acc2,
                                               float* __restrict__ ssum2) {
    const int wid = threadIdx.x >> 6, lane = threadIdx.x & 63;
    const int e = blockIdx.x * 4 + wid;
    if (e >= EE) return;
    const int s = src[e], d = dst[e];
    float sc = el2[s] + er2[d];
    sc = sc > 0.f ? sc : SLOPE * sc;
    const float ee = __expf(sc);
    if (lane < C) atomicAdd(&acc2[(size_t)d * C + lane], ee * h2[(size_t)s * C + lane]);
    if (lane == 0) atomicAdd(&ssum2[d], ee);
}

// ---------------- final normalize + bias -> out ----------------
__global__ __launch_bounds__(256) void k_out(const float* __restrict__ acc2,
                                             const float* __restrict__ ssum2,
                                             const float* __restrict__ b2,
                                             float* __restrict__ out) {
    const int idx = blockIdx.x * 256 + threadIdx.x;
    if (idx >= NN * C) return;
    const int n = idx / C, c = idx - n * C;
    float ss = ssum2[n];
    out[idx] = (ss > 0.f ? acc2[idx] / ss : 0.f) + b2[c];
}

extern "C" void kernel_launch(void* const* d_in, const int* in_sizes, int n_in,
                              void* d_out, int out_size, void* d_ws, size_t ws_size,
                              hipStream_t stream) {
    const float* feat = (const float*)d_in[0];
    const int*   src  = (const int*)d_in[1];
    const int*   dst  = (const int*)d_in[2];
    const float* W1   = (const float*)d_in[3];
    const float* al1  = (const float*)d_in[4];
    const float* ar1  = (const float*)d_in[5];
    const float* b1   = (const float*)d_in[6];
    const float* W2   = (const float*)d_in[7];
    const float* al2  = (const float*)d_in[8];
    const float* ar2  = (const float*)d_in[9];
    const float* b2   = (const float*)d_in[10];
    float* out = (float*)d_out;

    float* ws    = (float*)d_ws;
    float* h1    = ws;                        // N*128 floats (reused as x)
    float* acc1  = h1 + (size_t)NN * HF;      // N*128 floats (reused: h2 @0, acc2 @N*C)
    float* el1   = acc1 + (size_t)NN * HF;    // N*4 (reused as el2)
    float* er1   = el1 + (size_t)NN * 4;      // N*4 (reused as er2)
    float* ssum1 = er1 + (size_t)NN * 4;      // N*4 (reused as ssum2)
    float* h2    = acc1;
    float* acc2  = acc1 + (size_t)NN * C;
    float* el2 = el1; float* er2 = er1; float* ssum2 = ssum1;

    // Layer 1
    hipMemsetAsync(acc1, 0, (size_t)NN * HF * sizeof(float), stream);
    hipMemsetAsync(ssum1, 0, (size_t)NN * 4 * sizeof(float), stream);
    k_gemm1<<<NN / 32, 256, 0, stream>>>(feat, W1, h1);
    k_elr1<<<NN / 4, 256, 0, stream>>>(h1, al1, ar1, el1, er1);
    k_edge1<<<EE / 4, 256, 0, stream>>>(src, dst, h1, el1, er1, acc1, ssum1);
    k_norm_elu<<<NN * 32 / 256, 256, 0, stream>>>(acc1, ssum1, b1, h1);

    // Layer 2 (buffers reused only after their last reader above)
    hipMemsetAsync(acc2, 0, (size_t)NN * C * sizeof(float), stream);
    hipMemsetAsync(ssum2, 0, (size_t)NN * sizeof(float), stream);
    k_gemm2<<<NN / 4, 256, 0, stream>>>(h1, W2, al2, ar2, h2, el2, er2);
    k_edge2<<<EE / 4, 256, 0, stream>>>(src, dst, h2, el2, er2, acc2, ssum2);
    k_out<<<(NN * C + 255) / 256, 256, 0, stream>>>(acc2, ssum2, b2, out);
}

// Round 2
// 1196.469 us; speedup vs baseline: 1.7853x; 1.7853x over previous
//
#include <hip/hip_runtime.h>
#include <math.h>

constexpr int NN = 100000;
constexpr int EE = 1600000;
constexpr int IND = 256;
constexpr int F1 = 32;
constexpr int HF = 128;   // H*F1
constexpr int C  = 40;
constexpr float SLOPE = 0.2f;

// ================= CSR build =================
__global__ __launch_bounds__(256) void k_hist(const int* __restrict__ dst,
                                              int* __restrict__ deg) {
    int e = blockIdx.x * 256 + threadIdx.x;
    if (e < EE) atomicAdd(&deg[dst[e]], 1);
}

// single-block exclusive scan over N degrees -> row_ptr[N+1], cursor copy
__global__ __launch_bounds__(1024) void k_scan(const int* __restrict__ deg,
                                               int* __restrict__ row_ptr,
                                               int* __restrict__ cursor) {
    __shared__ int sums[1024];
    const int tid = threadIdx.x;
    const int chunk = (NN + 1023) / 1024;  // 98
    const int base = tid * chunk;
    int s = 0;
    for (int i = 0; i < chunk; ++i) {
        int idx = base + i;
        if (idx < NN) s += deg[idx];
    }
    sums[tid] = s;
    __syncthreads();
    // Hillis-Steele inclusive scan in LDS
    for (int off = 1; off < 1024; off <<= 1) {
        int v = (tid >= off) ? sums[tid - off] : 0;
        __syncthreads();
        sums[tid] += v;
        __syncthreads();
    }
    int run = (tid == 0) ? 0 : sums[tid - 1];
    for (int i = 0; i < chunk; ++i) {
        int idx = base + i;
        if (idx < NN) {
            int dv = deg[idx];
            row_ptr[idx] = run;
            cursor[idx] = run;
            run += dv;
        }
    }
    if (tid == 1023) row_ptr[NN] = run;   // == EE
}

__global__ __launch_bounds__(256) void k_scatter(const int* __restrict__ src,
                                                 const int* __restrict__ dst,
                                                 int* __restrict__ cursor,
                                                 int* __restrict__ col_src) {
    int e = blockIdx.x * 256 + threadIdx.x;
    if (e < EE) {
        int p = atomicAdd(&cursor[dst[e]], 1);
        col_src[p] = src[e];
    }
}

// ================= GEMM1: h1 = feat @ W1  (N x 256) @ (256 x 128) =================
__global__ __launch_bounds__(256) void k_gemm1(const float* __restrict__ feat,
                                               const float* __restrict__ W1,
                                               float* __restrict__ h1) {
    __shared__ float a_s[32][33];
    __shared__ float b_s[32][128];
    const int tid = threadIdx.x;
    const int tx = tid & 31, ty = tid >> 5;
    const int n0 = blockIdx.x * 32;
    float4 acc[4] = {};
    for (int kt = 0; kt < IND; kt += 32) {
        {
            int r = tid >> 3, c4 = (tid & 7) * 4;
            const float4 v = *(const float4*)&feat[(size_t)(n0 + r) * IND + kt + c4];
            a_s[r][c4] = v.x; a_s[r][c4 + 1] = v.y; a_s[r][c4 + 2] = v.z; a_s[r][c4 + 3] = v.w;
        }
        {
            int cc = tx * 4;
            #pragma unroll
            for (int rep = 0; rep < 4; ++rep) {
                int kr = ty + rep * 8;
                *(float4*)&b_s[kr][cc] = *(const float4*)&W1[(size_t)(kt + kr) * HF + cc];
            }
        }
        __syncthreads();
        #pragma unroll
        for (int k = 0; k < 32; ++k) {
            float4 b4 = *(float4*)&b_s[k][tx * 4];
            #pragma unroll
            for (int i = 0; i < 4; ++i) {
                float a = a_s[ty * 4 + i][k];
                acc[i].x += a * b4.x; acc[i].y += a * b4.y;
                acc[i].z += a * b4.z; acc[i].w += a * b4.w;
            }
        }
        __syncthreads();
    }
    #pragma unroll
    for (int i = 0; i < 4; ++i)
        *(float4*)&h1[(size_t)(n0 + ty * 4 + i) * HF + tx * 4] = acc[i];
}

// ================= el1/er1 =================
__global__ __launch_bounds__(256) void k_elr1(const float* __restrict__ h1,
                                              const float* __restrict__ al1,
                                              const float* __restrict__ ar1,
                                              float* __restrict__ el1,
                                              float* __restrict__ er1) {
    const int wid = threadIdx.x >> 6, lane = threadIdx.x & 63;
    const int n = blockIdx.x * 4 + wid;
    const int head = lane >> 4;
    const int fo = (lane & 15) * 2;
    float2 h = *(const float2*)&h1[(size_t)n * HF + lane * 2];
    float2 al = *(const float2*)&al1[head * F1 + fo];
    float2 ar = *(const float2*)&ar1[head * F1 + fo];
    float pel = h.x * al.x + h.y * al.y;
    float per = h.x * ar.x + h.y * ar.y;
    #pragma unroll
    for (int m = 1; m < 16; m <<= 1) {
        pel += __shfl_xor(pel, m, 64);
        per += __shfl_xor(per, m, 64);
    }
    if ((lane & 15) == 0) {
        el1[n * 4 + head] = pel;
        er1[n * 4 + head] = per;
    }
}

// ================= layer-1 aggregation: one wave per dst node =================
// acc in registers; normalize + bias + ELU fused -> x
__global__ __launch_bounds__(256) void k_agg1(const int* __restrict__ row_ptr,
                                              const int* __restrict__ col_src,
                                              const float* __restrict__ h1,
                                              const float* __restrict__ el1,
                                              const float* __restrict__ er1,
                                              const float* __restrict__ b1,
                                              float* __restrict__ x) {
    const int wid = threadIdx.x >> 6, lane = threadIdx.x & 63;
    const int d = blockIdx.x * 4 + wid;
    if (d >= NN) return;
    const int head = lane >> 4;
    const float erd = er1[d * 4 + head];
    const int beg = row_ptr[d], end = row_ptr[d + 1];
    float2 acc = {0.f, 0.f};
    float ssum = 0.f;
    int s = (beg < end) ? col_src[beg] : 0;
    for (int e = beg; e < end; ++e) {
        int s_next = (e + 1 < end) ? col_src[e + 1] : 0;   // prefetch index
        float sc = el1[s * 4 + head] + erd;
        sc = sc > 0.f ? sc : SLOPE * sc;
        float ee = __expf(sc);
        float2 h = *(const float2*)&h1[(size_t)s * HF + lane * 2];
        acc.x += ee * h.x;
        acc.y += ee * h.y;
        ssum += ee;
        s = s_next;
    }
    float inv = ssum > 0.f ? 1.f / ssum : 0.f;
    float2 b = *(const float2*)&b1[lane * 2];
    float rx = acc.x * inv + b.x;
    float ry = acc.y * inv + b.y;
    rx = rx > 0.f ? rx : expm1f(rx);
    ry = ry > 0.f ? ry : expm1f(ry);
    float2 r = {rx, ry};
    *(float2*)&x[(size_t)d * HF + lane * 2] = r;
}

// ================= GEMM2 + el2/er2 (one wave per node) =================
__global__ __launch_bounds__(256) void k_gemm2(const float* __restrict__ x,
                                               const float* __restrict__ W2,
                                               const float* __restrict__ al2,
                                               const float* __restrict__ ar2,
                                               float* __restrict__ h2,
                                               float* __restrict__ el2,
                                               float* __restrict__ er2) {
    __shared__ float w2s[HF * C];
    __shared__ float xs[4][HF];
    __shared__ float al2s[C], ar2s[C];
    const int tid = threadIdx.x;
    for (int i = tid; i < HF * C; i += 256) w2s[i] = W2[i];
    if (tid < C) { al2s[tid] = al2[tid]; ar2s[tid] = ar2[tid]; }
    const int wid = tid >> 6, lane = tid & 63;
    const int n = blockIdx.x * 4 + wid;
    xs[wid][lane] = x[(size_t)n * HF + lane];
    xs[wid][lane + 64] = x[(size_t)n * HF + lane + 64];
    __syncthreads();
    float acc = 0.f;
    if (lane < C) {
        #pragma unroll 4
        for (int k = 0; k < HF; ++k) acc += xs[wid][k] * w2s[k * C + lane];
    }
    float pel = lane < C ? acc * al2s[lane] : 0.f;
    float per = lane < C ? acc * ar2s[lane] : 0.f;
    #pragma unroll
    for (int m = 1; m < 64; m <<= 1) {
        pel += __shfl_xor(pel, m, 64);
        per += __shfl_xor(per, m, 64);
    }
    if (lane < C) h2[(size_t)n * C + lane] = acc;
    if (lane == 0) { el2[n] = pel; er2[n] = per; }
}

// ================= layer-2 aggregation: one wave per dst node =================
__global__ __launch_bounds__(256) void k_agg2(const int* __restrict__ row_ptr,
                                              const int* __restrict__ col_src,
                                              const float* __restrict__ h2,
                                              const float* __restrict__ el2,
                                              const float* __restrict__ er2,
                                              const float* __restrict__ b2,
                                              float* __restrict__ out) {
    const int wid = threadIdx.x >> 6, lane = threadIdx.x & 63;
    const int d = blockIdx.x * 4 + wid;
    if (d >= NN) return;
    const float erd = er2[d];
    const int beg = row_ptr[d], end = row_ptr[d + 1];
    float acc = 0.f, ssum = 0.f;
    int s = (beg < end) ? col_src[beg] : 0;
    for (int e = beg; e < end; ++e) {
        int s_next = (e + 1 < end) ? col_src[e + 1] : 0;
        float sc = el2[s] + erd;
        sc = sc > 0.f ? sc : SLOPE * sc;
        float ee = __expf(sc);
        if (lane < C) acc += ee * h2[(size_t)s * C + lane];
        ssum += ee;
        s = s_next;
    }
    if (lane < C) {
        float inv = ssum > 0.f ? 1.f / ssum : 0.f;
        out[(size_t)d * C + lane] = acc * inv + b2[lane];
    }
}

extern "C" void kernel_launch(void* const* d_in, const int* in_sizes, int n_in,
                              void* d_out, int out_size, void* d_ws, size_t ws_size,
                              hipStream_t stream) {
    const float* feat = (const float*)d_in[0];
    const int*   src  = (const int*)d_in[1];
    const int*   dst  = (const int*)d_in[2];
    const float* W1   = (const float*)d_in[3];
    const float* al1  = (const float*)d_in[4];
    const float* ar1  = (const float*)d_in[5];
    const float* b1   = (const float*)d_in[6];
    const float* W2   = (const float*)d_in[7];
    const float* al2  = (const float*)d_in[8];
    const float* ar2  = (const float*)d_in[9];
    const float* b2   = (const float*)d_in[10];
    float* out = (float*)d_out;

    // ---- workspace layout ----
    float* h1  = (float*)d_ws;                 // N*128  (reused as h2 after x is built)
    float* x   = h1 + (size_t)NN * HF;         // N*128
    float* el1 = x + (size_t)NN * HF;          // N*4   (reused as el2: N)
    float* er1 = el1 + (size_t)NN * 4;         // N*4   (reused as er2: N)
    int* row_ptr = (int*)(er1 + (size_t)NN * 4);  // N+1
    int* cursor  = row_ptr + (NN + 1);            // N
    int* deg     = cursor + NN;                   // N
    int* col_src = deg + NN;                      // E
    float* h2 = h1;
    float* el2 = el1; float* er2 = er1;

    // ---- CSR build (shared by both layers) ----
    hipMemsetAsync(deg, 0, (size_t)NN * sizeof(int), stream);
    k_hist<<<(EE + 255) / 256, 256, 0, stream>>>(dst, deg);
    k_scan<<<1, 1024, 0, stream>>>(deg, row_ptr, cursor);
    k_scatter<<<(EE + 255) / 256, 256, 0, stream>>>(src, dst, cursor, col_src);

    // ---- layer 1 ----
    k_gemm1<<<NN / 32, 256, 0, stream>>>(feat, W1, h1);
    k_elr1<<<NN / 4, 256, 0, stream>>>(h1, al1, ar1, el1, er1);
    k_agg1<<<NN / 4, 256, 0, stream>>>(row_ptr, col_src, h1, el1, er1, b1, x);

    // ---- layer 2 ----
    k_gemm2<<<NN / 4, 256, 0, stream>>>(x, W2, al2, ar2, h2, el2, er2);
    k_agg2<<<NN / 4, 256, 0, stream>>>(row_ptr, col_src, h2, el2, er2, b2, out);
}

// Round 3
// 938.654 us; speedup vs baseline: 2.2757x; 1.2747x over previous
//
#include <hip/hip_runtime.h>
#include <math.h>

constexpr int NN = 100000;
constexpr int EE = 1600000;
constexpr int IND = 256;
constexpr int F1 = 32;
constexpr int HF = 128;   // H*F1
constexpr int C  = 40;
constexpr float SLOPE = 0.2f;

constexpr int SCAN_BLOCKS = 100;
constexpr int SCAN_CHUNK  = 1000;   // SCAN_BLOCKS * SCAN_CHUNK == NN

// ================= CSR build =================
__global__ __launch_bounds__(256) void k_hist(const int* __restrict__ dst,
                                              int* __restrict__ deg) {
    int e = blockIdx.x * 256 + threadIdx.x;
    if (e < EE) atomicAdd(&deg[dst[e]], 1);
}

// pass 1: per-block chunk sums
__global__ __launch_bounds__(256) void k_scan1(const int* __restrict__ deg,
                                               int* __restrict__ blk_sums) {
    __shared__ int wsum[4];
    const int lane = threadIdx.x & 63, wid = threadIdx.x >> 6;
    const int base = blockIdx.x * SCAN_CHUNK;
    int s = 0;
    for (int i = threadIdx.x; i < SCAN_CHUNK; i += 256) s += deg[base + i];
    #pragma unroll
    for (int m = 1; m < 64; m <<= 1) s += __shfl_xor(s, m, 64);
    if (lane == 0) wsum[wid] = s;
    __syncthreads();
    if (threadIdx.x == 0)
        blk_sums[blockIdx.x] = wsum[0] + wsum[1] + wsum[2] + wsum[3];
}

// pass 2: exclusive scan of the 100 block sums (tiny)
__global__ __launch_bounds__(128) void k_scan2(int* __restrict__ blk_sums) {
    __shared__ int lds[128];
    const int tid = threadIdx.x;
    int v = (tid < SCAN_BLOCKS) ? blk_sums[tid] : 0;
    lds[tid] = v;
    __syncthreads();
    for (int off = 1; off < 128; off <<= 1) {
        int t = (tid >= off) ? lds[tid - off] : 0;
        __syncthreads();
        lds[tid] += t;
        __syncthreads();
    }
    if (tid < SCAN_BLOCKS) blk_sums[tid] = (tid == 0) ? 0 : lds[tid - 1];
}

// pass 3: intra-chunk exclusive scan + block offset -> row_ptr, cursor
__global__ __launch_bounds__(256) void k_scan3(const int* __restrict__ deg,
                                               const int* __restrict__ blk_off,
                                               int* __restrict__ row_ptr,
                                               int* __restrict__ cursor) {
    __shared__ int wsum[4];
    const int tid = threadIdx.x, lane = tid & 63, wid = tid >> 6;
    const int base = blockIdx.x * SCAN_CHUNK;
    const int g0 = tid * 4;
    int v[4];
    #pragma unroll
    for (int i = 0; i < 4; ++i) {
        int gi = g0 + i;
        v[i] = (gi < SCAN_CHUNK) ? deg[base + gi] : 0;
    }
    const int tsum = v[0] + v[1] + v[2] + v[3];
    // inclusive wave scan of per-thread sums
    int s = tsum;
    #pragma unroll
    for (int off = 1; off < 64; off <<= 1) {
        int t = __shfl_up(s, off, 64);
        if (lane >= off) s += t;
    }
    if (lane == 63) wsum[wid] = s;
    __syncthreads();
    int woff = 0;
    for (int w = 0; w < wid; ++w) woff += wsum[w];
    int run = blk_off[blockIdx.x] + woff + (s - tsum);
    #pragma unroll
    for (int i = 0; i < 4; ++i) {
        int gi = g0 + i;
        int idx = base + gi;
        if (gi < SCAN_CHUNK) {
            row_ptr[idx] = run;
            cursor[idx] = run;
            run += v[i];
            if (idx == NN - 1) row_ptr[NN] = run;
        }
    }
}

__global__ __launch_bounds__(256) void k_scatter(const int* __restrict__ src,
                                                 const int* __restrict__ dst,
                                                 int* __restrict__ cursor,
                                                 int* __restrict__ col_src) {
    int e = blockIdx.x * 256 + threadIdx.x;
    if (e < EE) {
        int p = atomicAdd(&cursor[dst[e]], 1);
        col_src[p] = src[e];
    }
}

// ================= GEMM1: h1 = feat @ W1  (N x 256) @ (256 x 128) =================
__global__ __launch_bounds__(256) void k_gemm1(const float* __restrict__ feat,
                                               const float* __restrict__ W1,
                                               float* __restrict__ h1) {
    __shared__ float a_s[32][33];
    __shared__ float b_s[32][128];
    const int tid = threadIdx.x;
    const int tx = tid & 31, ty = tid >> 5;
    const int n0 = blockIdx.x * 32;
    float4 acc[4] = {};
    for (int kt = 0; kt < IND; kt += 32) {
        {
            int r = tid >> 3, c4 = (tid & 7) * 4;
            const float4 v = *(const float4*)&feat[(size_t)(n0 + r) * IND + kt + c4];
            a_s[r][c4] = v.x; a_s[r][c4 + 1] = v.y; a_s[r][c4 + 2] = v.z; a_s[r][c4 + 3] = v.w;
        }
        {
            int cc = tx * 4;
            #pragma unroll
            for (int rep = 0; rep < 4; ++rep) {
                int kr = ty + rep * 8;
                *(float4*)&b_s[kr][cc] = *(const float4*)&W1[(size_t)(kt + kr) * HF + cc];
            }
        }
        __syncthreads();
        #pragma unroll
        for (int k = 0; k < 32; ++k) {
            float4 b4 = *(float4*)&b_s[k][tx * 4];
            #pragma unroll
            for (int i = 0; i < 4; ++i) {
                float a = a_s[ty * 4 + i][k];
                acc[i].x += a * b4.x; acc[i].y += a * b4.y;
                acc[i].z += a * b4.z; acc[i].w += a * b4.w;
            }
        }
        __syncthreads();
    }
    #pragma unroll
    for (int i = 0; i < 4; ++i)
        *(float4*)&h1[(size_t)(n0 + ty * 4 + i) * HF + tx * 4] = acc[i];
}

// ================= el1/er1 =================
__global__ __launch_bounds__(256) void k_elr1(const float* __restrict__ h1,
                                              const float* __restrict__ al1,
                                              const float* __restrict__ ar1,
                                              float* __restrict__ el1,
                                              float* __restrict__ er1) {
    const int wid = threadIdx.x >> 6, lane = threadIdx.x & 63;
    const int n = blockIdx.x * 4 + wid;
    const int head = lane >> 4;
    const int fo = (lane & 15) * 2;
    float2 h = *(const float2*)&h1[(size_t)n * HF + lane * 2];
    float2 al = *(const float2*)&al1[head * F1 + fo];
    float2 ar = *(const float2*)&ar1[head * F1 + fo];
    float pel = h.x * al.x + h.y * al.y;
    float per = h.x * ar.x + h.y * ar.y;
    #pragma unroll
    for (int m = 1; m < 16; m <<= 1) {
        pel += __shfl_xor(pel, m, 64);
        per += __shfl_xor(per, m, 64);
    }
    if ((lane & 15) == 0) {
        el1[n * 4 + head] = pel;
        er1[n * 4 + head] = per;
    }
}

// ================= layer-1 aggregation: one wave per dst node =================
__global__ __launch_bounds__(256) void k_agg1(const int* __restrict__ row_ptr,
                                              const int* __restrict__ col_src,
                                              const float* __restrict__ h1,
                                              const float* __restrict__ el1,
                                              const float* __restrict__ er1,
                                              const float* __restrict__ b1,
                                              float* __restrict__ x) {
    const int wid = threadIdx.x >> 6, lane = threadIdx.x & 63;
    const int d = blockIdx.x * 4 + wid;
    if (d >= NN) return;
    const int head = lane >> 4;
    const float erd = er1[d * 4 + head];
    const int beg = row_ptr[d], end = row_ptr[d + 1];
    float2 acc = {0.f, 0.f};
    float ssum = 0.f;
    int s = (beg < end) ? col_src[beg] : 0;
    for (int e = beg; e < end; ++e) {
        int s_next = (e + 1 < end) ? col_src[e + 1] : 0;
        float sc = el1[s * 4 + head] + erd;
        sc = sc > 0.f ? sc : SLOPE * sc;
        float ee = __expf(sc);
        float2 h = *(const float2*)&h1[(size_t)s * HF + lane * 2];
        acc.x += ee * h.x;
        acc.y += ee * h.y;
        ssum += ee;
        s = s_next;
    }
    float inv = ssum > 0.f ? 1.f / ssum : 0.f;
    float2 b = *(const float2*)&b1[lane * 2];
    float rx = acc.x * inv + b.x;
    float ry = acc.y * inv + b.y;
    rx = rx > 0.f ? rx : expm1f(rx);
    ry = ry > 0.f ? ry : expm1f(ry);
    float2 r = {rx, ry};
    *(float2*)&x[(size_t)d * HF + lane * 2] = r;
}

// ================= GEMM2 + el2/er2 (one wave per node) =================
__global__ __launch_bounds__(256) void k_gemm2(const float* __restrict__ x,
                                               const float* __restrict__ W2,
                                               const float* __restrict__ al2,
                                               const float* __restrict__ ar2,
                                               float* __restrict__ h2,
                                               float* __restrict__ el2,
                                               float* __restrict__ er2) {
    __shared__ float w2s[HF * C];
    __shared__ float xs[4][HF];
    __shared__ float al2s[C], ar2s[C];
    const int tid = threadIdx.x;
    for (int i = tid; i < HF * C; i += 256) w2s[i] = W2[i];
    if (tid < C) { al2s[tid] = al2[tid]; ar2s[tid] = ar2[tid]; }
    const int wid = tid >> 6, lane = tid & 63;
    const int n = blockIdx.x * 4 + wid;
    xs[wid][lane] = x[(size_t)n * HF + lane];
    xs[wid][lane + 64] = x[(size_t)n * HF + lane + 64];
    __syncthreads();
    float acc = 0.f;
    if (lane < C) {
        #pragma unroll 4
        for (int k = 0; k < HF; ++k) acc += xs[wid][k] * w2s[k * C + lane];
    }
    float pel = lane < C ? acc * al2s[lane] : 0.f;
    float per = lane < C ? acc * ar2s[lane] : 0.f;
    #pragma unroll
    for (int m = 1; m < 64; m <<= 1) {
        pel += __shfl_xor(pel, m, 64);
        per += __shfl_xor(per, m, 64);
    }
    if (lane < C) h2[(size_t)n * C + lane] = acc;
    if (lane == 0) { el2[n] = pel; er2[n] = per; }
}

// ================= layer-2 aggregation: one wave per dst node =================
__global__ __launch_bounds__(256) void k_agg2(const int* __restrict__ row_ptr,
                                              const int* __restrict__ col_src,
                                              const float* __restrict__ h2,
                                              const float* __restrict__ el2,
                                              const float* __restrict__ er2,
                                              const float* __restrict__ b2,
                                              float* __restrict__ out) {
    const int wid = threadIdx.x >> 6, lane = threadIdx.x & 63;
    const int d = blockIdx.x * 4 + wid;
    if (d >= NN) return;
    const float erd = er2[d];
    const int beg = row_ptr[d], end = row_ptr[d + 1];
    float acc = 0.f, ssum = 0.f;
    int s = (beg < end) ? col_src[beg] : 0;
    for (int e = beg; e < end; ++e) {
        int s_next = (e + 1 < end) ? col_src[e + 1] : 0;
        float sc = el2[s] + erd;
        sc = sc > 0.f ? sc : SLOPE * sc;
        float ee = __expf(sc);
        if (lane < C) acc += ee * h2[(size_t)s * C + lane];
        ssum += ee;
        s = s_next;
    }
    if (lane < C) {
        float inv = ssum > 0.f ? 1.f / ssum : 0.f;
        out[(size_t)d * C + lane] = acc * inv + b2[lane];
    }
}

extern "C" void kernel_launch(void* const* d_in, const int* in_sizes, int n_in,
                              void* d_out, int out_size, void* d_ws, size_t ws_size,
                              hipStream_t stream) {
    const float* feat = (const float*)d_in[0];
    const int*   src  = (const int*)d_in[1];
    const int*   dst  = (const int*)d_in[2];
    const float* W1   = (const float*)d_in[3];
    const float* al1  = (const float*)d_in[4];
    const float* ar1  = (const float*)d_in[5];
    const float* b1   = (const float*)d_in[6];
    const float* W2   = (const float*)d_in[7];
    const float* al2  = (const float*)d_in[8];
    const float* ar2  = (const float*)d_in[9];
    const float* b2   = (const float*)d_in[10];
    float* out = (float*)d_out;

    // ---- workspace layout ----
    float* h1  = (float*)d_ws;                 // N*128  (reused as h2)
    float* x   = h1 + (size_t)NN * HF;         // N*128
    float* el1 = x + (size_t)NN * HF;          // N*4   (reused as el2: N)
    float* er1 = el1 + (size_t)NN * 4;         // N*4   (reused as er2: N)
    int* row_ptr = (int*)(er1 + (size_t)NN * 4);  // N+1
    int* cursor  = row_ptr + (NN + 1);            // N
    int* deg     = cursor + NN;                   // N
    int* blk_sums = deg + NN;                     // SCAN_BLOCKS
    int* col_src = blk_sums + SCAN_BLOCKS;        // E
    float* h2 = h1;
    float* el2 = el1; float* er2 = er1;

    // ---- CSR build (shared by both layers) ----
    hipMemsetAsync(deg, 0, (size_t)NN * sizeof(int), stream);
    k_hist<<<(EE + 255) / 256, 256, 0, stream>>>(dst, deg);
    k_scan1<<<SCAN_BLOCKS, 256, 0, stream>>>(deg, blk_sums);
    k_scan2<<<1, 128, 0, stream>>>(blk_sums);
    k_scan3<<<SCAN_BLOCKS, 256, 0, stream>>>(deg, blk_sums, row_ptr, cursor);
    k_scatter<<<(EE + 255) / 256, 256, 0, stream>>>(src, dst, cursor, col_src);

    // ---- layer 1 ----
    k_gemm1<<<NN / 32, 256, 0, stream>>>(feat, W1, h1);
    k_elr1<<<NN / 4, 256, 0, stream>>>(h1, al1, ar1, el1, er1);
    k_agg1<<<NN / 4, 256, 0, stream>>>(row_ptr, col_src, h1, el1, er1, b1, x);

    // ---- layer 2 ----
    k_gemm2<<<NN / 4, 256, 0, stream>>>(x, W2, al2, ar2, h2, el2, er2);
    k_agg2<<<NN / 4, 256, 0, stream>>>(row_ptr, col_src, h2, el2, er2, b2, out);
}

// Round 4
// 699.963 us; speedup vs baseline: 3.0517x; 1.3410x over previous
//
#include <hip/hip_runtime.h>
#include <math.h>

typedef unsigned int u32;

constexpr int NN = 100000;
constexpr int EE = 1600000;
constexpr int IND = 256;
constexpr int F1 = 32;
constexpr int HF = 128;   // H*F1
constexpr int C  = 40;
constexpr float SLOPE = 0.2f;

constexpr int SCAN_BLOCKS = 100;
constexpr int SCAN_CHUNK  = 1000;   // SCAN_BLOCKS * SCAN_CHUNK == NN

// bf16 helpers (RNE pack, cheap unpack)
__device__ __forceinline__ u32 f2bf(float f) {
    u32 u = __float_as_uint(f);
    return (u + 0x7fffu + ((u >> 16) & 1u)) >> 16;
}
__device__ __forceinline__ float bf_lo(u32 v) { return __uint_as_float(v << 16); }
__device__ __forceinline__ float bf_hi(u32 v) { return __uint_as_float(v & 0xffff0000u); }

// ================= CSR build =================
__global__ __launch_bounds__(256) void k_hist(const int* __restrict__ dst,
                                              int* __restrict__ deg) {
    int e = blockIdx.x * 256 + threadIdx.x;
    if (e < EE) atomicAdd(&deg[dst[e]], 1);
}

__global__ __launch_bounds__(256) void k_scan1(const int* __restrict__ deg,
                                               int* __restrict__ blk_sums) {
    __shared__ int wsum[4];
    const int lane = threadIdx.x & 63, wid = threadIdx.x >> 6;
    const int base = blockIdx.x * SCAN_CHUNK;
    int s = 0;
    for (int i = threadIdx.x; i < SCAN_CHUNK; i += 256) s += deg[base + i];
    #pragma unroll
    for (int m = 1; m < 64; m <<= 1) s += __shfl_xor(s, m, 64);
    if (lane == 0) wsum[wid] = s;
    __syncthreads();
    if (threadIdx.x == 0)
        blk_sums[blockIdx.x] = wsum[0] + wsum[1] + wsum[2] + wsum[3];
}

__global__ __launch_bounds__(128) void k_scan2(int* __restrict__ blk_sums) {
    __shared__ int lds[128];
    const int tid = threadIdx.x;
    int v = (tid < SCAN_BLOCKS) ? blk_sums[tid] : 0;
    lds[tid] = v;
    __syncthreads();
    for (int off = 1; off < 128; off <<= 1) {
        int t = (tid >= off) ? lds[tid - off] : 0;
        __syncthreads();
        lds[tid] += t;
        __syncthreads();
    }
    if (tid < SCAN_BLOCKS) blk_sums[tid] = (tid == 0) ? 0 : lds[tid - 1];
}

__global__ __launch_bounds__(256) void k_scan3(const int* __restrict__ deg,
                                               const int* __restrict__ blk_off,
                                               int* __restrict__ row_ptr,
                                               int* __restrict__ cursor) {
    __shared__ int wsum[4];
    const int tid = threadIdx.x, lane = tid & 63, wid = tid >> 6;
    const int base = blockIdx.x * SCAN_CHUNK;
    const int g0 = tid * 4;
    int v[4];
    #pragma unroll
    for (int i = 0; i < 4; ++i) {
        int gi = g0 + i;
        v[i] = (gi < SCAN_CHUNK) ? deg[base + gi] : 0;
    }
    const int tsum = v[0] + v[1] + v[2] + v[3];
    int s = tsum;
    #pragma unroll
    for (int off = 1; off < 64; off <<= 1) {
        int t = __shfl_up(s, off, 64);
        if (lane >= off) s += t;
    }
    if (lane == 63) wsum[wid] = s;
    __syncthreads();
    int woff = 0;
    for (int w = 0; w < wid; ++w) woff += wsum[w];
    int run = blk_off[blockIdx.x] + woff + (s - tsum);
    #pragma unroll
    for (int i = 0; i < 4; ++i) {
        int gi = g0 + i;
        int idx = base + gi;
        if (gi < SCAN_CHUNK) {
            row_ptr[idx] = run;
            cursor[idx] = run;
            run += v[i];
            if (idx == NN - 1) row_ptr[NN] = run;
        }
    }
}

__global__ __launch_bounds__(256) void k_scatter(const int* __restrict__ src,
                                                 const int* __restrict__ dst,
                                                 int* __restrict__ cursor,
                                                 int* __restrict__ col_src) {
    int e = blockIdx.x * 256 + threadIdx.x;
    if (e < EE) {
        int p = atomicAdd(&cursor[dst[e]], 1);
        col_src[p] = src[e];
    }
}

// ================= GEMM1: h1b(bf16) = feat @ W1 =================
__global__ __launch_bounds__(256) void k_gemm1(const float* __restrict__ feat,
                                               const float* __restrict__ W1,
                                               u32* __restrict__ h1b) {
    __shared__ float a_s[32][33];
    __shared__ float b_s[32][128];
    const int tid = threadIdx.x;
    const int tx = tid & 31, ty = tid >> 5;
    const int n0 = blockIdx.x * 32;
    float4 acc[4] = {};
    for (int kt = 0; kt < IND; kt += 32) {
        {
            int r = tid >> 3, c4 = (tid & 7) * 4;
            const float4 v = *(const float4*)&feat[(size_t)(n0 + r) * IND + kt + c4];
            a_s[r][c4] = v.x; a_s[r][c4 + 1] = v.y; a_s[r][c4 + 2] = v.z; a_s[r][c4 + 3] = v.w;
        }
        {
            int cc = tx * 4;
            #pragma unroll
            for (int rep = 0; rep < 4; ++rep) {
                int kr = ty + rep * 8;
                *(float4*)&b_s[kr][cc] = *(const float4*)&W1[(size_t)(kt + kr) * HF + cc];
            }
        }
        __syncthreads();
        #pragma unroll
        for (int k = 0; k < 32; ++k) {
            float4 b4 = *(float4*)&b_s[k][tx * 4];
            #pragma unroll
            for (int i = 0; i < 4; ++i) {
                float a = a_s[ty * 4 + i][k];
                acc[i].x += a * b4.x; acc[i].y += a * b4.y;
                acc[i].z += a * b4.z; acc[i].w += a * b4.w;
            }
        }
        __syncthreads();
    }
    #pragma unroll
    for (int i = 0; i < 4; ++i) {
        u32 p0 = (f2bf(acc[i].y) << 16) | f2bf(acc[i].x);
        u32 p1 = (f2bf(acc[i].w) << 16) | f2bf(acc[i].z);
        *(uint2*)&h1b[(size_t)(n0 + ty * 4 + i) * 64 + tx * 2] = uint2{p0, p1};
    }
}

// ================= el1/er1 from bf16 h1 =================
__global__ __launch_bounds__(256) void k_elr1(const u32* __restrict__ h1b,
                                              const float* __restrict__ al1,
                                              const float* __restrict__ ar1,
                                              float* __restrict__ el1,
                                              float* __restrict__ er1) {
    const int wid = threadIdx.x >> 6, lane = threadIdx.x & 63;
    const int n = blockIdx.x * 4 + wid;
    const int head = lane >> 4;
    const int fo = (lane & 15) * 2;
    u32 v = h1b[(size_t)n * 64 + lane];
    float hx = bf_lo(v), hy = bf_hi(v);
    float2 al = *(const float2*)&al1[head * F1 + fo];
    float2 ar = *(const float2*)&ar1[head * F1 + fo];
    float pel = hx * al.x + hy * al.y;
    float per = hx * ar.x + hy * ar.y;
    #pragma unroll
    for (int m = 1; m < 16; m <<= 1) {
        pel += __shfl_xor(pel, m, 64);
        per += __shfl_xor(per, m, 64);
    }
    if ((lane & 15) == 0) {
        el1[n * 4 + head] = pel;
        er1[n * 4 + head] = per;
    }
}

// ================= layer-1 aggregation: wave per dst, 4-edge ILP =================
__global__ __launch_bounds__(256) void k_agg1(const int* __restrict__ row_ptr,
                                              const int* __restrict__ col_src,
                                              const u32* __restrict__ h1b,
                                              const float* __restrict__ el1,
                                              const float* __restrict__ er1,
                                              const float* __restrict__ b1,
                                              float* __restrict__ x) {
    const int wid = threadIdx.x >> 6, lane = threadIdx.x & 63;
    const int d = blockIdx.x * 4 + wid;
    if (d >= NN) return;
    const int head = lane >> 4;
    const float erd = er1[d * 4 + head];
    const int beg = row_ptr[d], end = row_ptr[d + 1];
    float accx = 0.f, accy = 0.f, ssum = 0.f;
    int e = beg;
    for (; e + 4 <= end; e += 4) {
        const int s0 = col_src[e],     s1 = col_src[e + 1];
        const int s2 = col_src[e + 2], s3 = col_src[e + 3];
        const u32 v0 = h1b[(size_t)s0 * 64 + lane];
        const u32 v1 = h1b[(size_t)s1 * 64 + lane];
        const u32 v2 = h1b[(size_t)s2 * 64 + lane];
        const u32 v3 = h1b[(size_t)s3 * 64 + lane];
        float c0 = el1[s0 * 4 + head] + erd;
        float c1 = el1[s1 * 4 + head] + erd;
        float c2 = el1[s2 * 4 + head] + erd;
        float c3 = el1[s3 * 4 + head] + erd;
        c0 = c0 > 0.f ? c0 : SLOPE * c0;
        c1 = c1 > 0.f ? c1 : SLOPE * c1;
        c2 = c2 > 0.f ? c2 : SLOPE * c2;
        c3 = c3 > 0.f ? c3 : SLOPE * c3;
        const float e0 = __expf(c0), e1 = __expf(c1);
        const float e2 = __expf(c2), e3 = __expf(c3);
        ssum += (e0 + e1) + (e2 + e3);
        accx += e0 * bf_lo(v0) + e1 * bf_lo(v1) + e2 * bf_lo(v2) + e3 * bf_lo(v3);
        accy += e0 * bf_hi(v0) + e1 * bf_hi(v1) + e2 * bf_hi(v2) + e3 * bf_hi(v3);
    }
    for (; e < end; ++e) {
        const int s = col_src[e];
        const u32 v = h1b[(size_t)s * 64 + lane];
        float c = el1[s * 4 + head] + erd;
        c = c > 0.f ? c : SLOPE * c;
        const float ee = __expf(c);
        ssum += ee;
        accx += ee * bf_lo(v);
        accy += ee * bf_hi(v);
    }
    const float inv = ssum > 0.f ? 1.f / ssum : 0.f;
    const float2 b = *(const float2*)&b1[lane * 2];
    float rx = accx * inv + b.x;
    float ry = accy * inv + b.y;
    rx = rx > 0.f ? rx : expm1f(rx);
    ry = ry > 0.f ? ry : expm1f(ry);
    *(float2*)&x[(size_t)d * HF + lane * 2] = float2{rx, ry};
}

// ================= GEMM2 + el2/er2 (one wave per node) =================
__global__ __launch_bounds__(256) void k_gemm2(const float* __restrict__ x,
                                               const float* __restrict__ W2,
                                               const float* __restrict__ al2,
                                               const float* __restrict__ ar2,
                                               float* __restrict__ h2,
                                               float* __restrict__ el2,
                                               float* __restrict__ er2) {
    __shared__ float w2s[HF * C];
    __shared__ float xs[4][HF];
    __shared__ float al2s[C], ar2s[C];
    const int tid = threadIdx.x;
    for (int i = tid; i < HF * C; i += 256) w2s[i] = W2[i];
    if (tid < C) { al2s[tid] = al2[tid]; ar2s[tid] = ar2[tid]; }
    const int wid = tid >> 6, lane = tid & 63;
    const int n = blockIdx.x * 4 + wid;
    xs[wid][lane] = x[(size_t)n * HF + lane];
    xs[wid][lane + 64] = x[(size_t)n * HF + lane + 64];
    __syncthreads();
    float acc = 0.f;
    if (lane < C) {
        #pragma unroll 4
        for (int k = 0; k < HF; ++k) acc += xs[wid][k] * w2s[k * C + lane];
    }
    float pel = lane < C ? acc * al2s[lane] : 0.f;
    float per = lane < C ? acc * ar2s[lane] : 0.f;
    #pragma unroll
    for (int m = 1; m < 64; m <<= 1) {
        pel += __shfl_xor(pel, m, 64);
        per += __shfl_xor(per, m, 64);
    }
    if (lane < C) h2[(size_t)n * C + lane] = acc;
    if (lane == 0) { el2[n] = pel; er2[n] = per; }
}

// ================= layer-2 aggregation: wave per dst, 4-edge ILP =================
__global__ __launch_bounds__(256) void k_agg2(const int* __restrict__ row_ptr,
                                              const int* __restrict__ col_src,
                                              const float* __restrict__ h2,
                                              const float* __restrict__ el2,
                                              const float* __restrict__ er2,
                                              const float* __restrict__ b2,
                                              float* __restrict__ out) {
    const int wid = threadIdx.x >> 6, lane = threadIdx.x & 63;
    const int d = blockIdx.x * 4 + wid;
    if (d >= NN) return;
    const float erd = er2[d];
    const int beg = row_ptr[d], end = row_ptr[d + 1];
    const bool act = lane < C;
    float acc = 0.f, ssum = 0.f;
    int e = beg;
    for (; e + 4 <= end; e += 4) {
        const int s0 = col_src[e],     s1 = col_src[e + 1];
        const int s2 = col_src[e + 2], s3 = col_src[e + 3];
        float h0 = 0.f, h1v = 0.f, h2v = 0.f, h3v = 0.f;
        if (act) {
            h0  = h2[(size_t)s0 * C + lane];
            h1v = h2[(size_t)s1 * C + lane];
            h2v = h2[(size_t)s2 * C + lane];
            h3v = h2[(size_t)s3 * C + lane];
        }
        float c0 = el2[s0] + erd;
        float c1 = el2[s1] + erd;
        float c2 = el2[s2] + erd;
        float c3 = el2[s3] + erd;
        c0 = c0 > 0.f ? c0 : SLOPE * c0;
        c1 = c1 > 0.f ? c1 : SLOPE * c1;
        c2 = c2 > 0.f ? c2 : SLOPE * c2;
        c3 = c3 > 0.f ? c3 : SLOPE * c3;
        const float e0 = __expf(c0), e1 = __expf(c1);
        const float e2 = __expf(c2), e3 = __expf(c3);
        ssum += (e0 + e1) + (e2 + e3);
        acc += e0 * h0 + e1 * h1v + e2 * h2v + e3 * h3v;
    }
    for (; e < end; ++e) {
        const int s = col_src[e];
        float hv = act ? h2[(size_t)s * C + lane] : 0.f;
        float c = el2[s] + erd;
        c = c > 0.f ? c : SLOPE * c;
        const float ee = __expf(c);
        ssum += ee;
        acc += ee * hv;
    }
    if (act) {
        const float inv = ssum > 0.f ? 1.f / ssum : 0.f;
        out[(size_t)d * C + lane] = acc * inv + b2[lane];
    }
}

extern "C" void kernel_launch(void* const* d_in, const int* in_sizes, int n_in,
                              void* d_out, int out_size, void* d_ws, size_t ws_size,
                              hipStream_t stream) {
    const float* feat = (const float*)d_in[0];
    const int*   src  = (const int*)d_in[1];
    const int*   dst  = (const int*)d_in[2];
    const float* W1   = (const float*)d_in[3];
    const float* al1  = (const float*)d_in[4];
    const float* ar1  = (const float*)d_in[5];
    const float* b1   = (const float*)d_in[6];
    const float* W2   = (const float*)d_in[7];
    const float* al2  = (const float*)d_in[8];
    const float* ar2  = (const float*)d_in[9];
    const float* b2   = (const float*)d_in[10];
    float* out = (float*)d_out;

    // ---- workspace layout ----
    u32*   h1b = (u32*)d_ws;                        // N*64 u32 (bf16x2); reused as h2 (N*C f32)
    float* x   = (float*)(h1b + (size_t)NN * 64);   // N*128 f32
    float* el1 = x + (size_t)NN * HF;               // N*4 (reused as el2: N)
    float* er1 = el1 + (size_t)NN * 4;              // N*4 (reused as er2: N)
    int* row_ptr = (int*)(er1 + (size_t)NN * 4);    // N+1
    int* cursor  = row_ptr + (NN + 1);              // N
    int* deg     = cursor + NN;                     // N
    int* blk_sums = deg + NN;                       // SCAN_BLOCKS
    int* col_src = blk_sums + SCAN_BLOCKS;          // E
    float* h2  = (float*)h1b;                       // N*C f32 (after agg1 done with h1b)
    float* el2 = el1; float* er2 = er1;

    // ---- CSR build (shared by both layers) ----
    hipMemsetAsync(deg, 0, (size_t)NN * sizeof(int), stream);
    k_hist<<<(EE + 255) / 256, 256, 0, stream>>>(dst, deg);
    k_scan1<<<SCAN_BLOCKS, 256, 0, stream>>>(deg, blk_sums);
    k_scan2<<<1, 128, 0, stream>>>(blk_sums);
    k_scan3<<<SCAN_BLOCKS, 256, 0, stream>>>(deg, blk_sums, row_ptr, cursor);
    k_scatter<<<(EE + 255) / 256, 256, 0, stream>>>(src, dst, cursor, col_src);

    // ---- layer 1 ----
    k_gemm1<<<NN / 32, 256, 0, stream>>>(feat, W1, h1b);
    k_elr1<<<NN / 4, 256, 0, stream>>>(h1b, al1, ar1, el1, er1);
    k_agg1<<<NN / 4, 256, 0, stream>>>(row_ptr, col_src, h1b, el1, er1, b1, x);

    // ---- layer 2 ----
    k_gemm2<<<NN / 4, 256, 0, stream>>>(x, W2, al2, ar2, h2, el2, er2);
    k_agg2<<<NN / 4, 256, 0, stream>>>(row_ptr, col_src, h2, el2, er2, b2, out);
}

// Round 5
// 674.038 us; speedup vs baseline: 3.1691x; 1.0385x over previous
//
#include <hip/hip_runtime.h>
#include <math.h>

typedef unsigned int u32;

constexpr int NN = 100000;
constexpr int EE = 1600000;
constexpr int IND = 256;
constexpr int F1 = 32;
constexpr int HF = 128;   // H*F1
constexpr int C  = 40;
constexpr float SLOPE = 0.2f;

constexpr int SCAN_BLOCKS = 100;
constexpr int SCAN_CHUNK  = 1000;   // SCAN_BLOCKS * SCAN_CHUNK == NN

constexpr int SC_NW    = 8;                          // scatter windows (== XCDs)
constexpr int SC_WINW  = (NN + SC_NW - 1) / SC_NW;   // 12500 dst nodes / window
constexpr int SC_CHUNK = 8192;                       // edges per chunk
constexpr int SC_NCHUNK = (EE + SC_CHUNK - 1) / SC_CHUNK;  // 196

constexpr int H2ROW = 24;  // u32 per h2b row: 20 bf16x2 pairs + el2 bits + pad

// bf16 helpers (RNE pack, cheap unpack)
__device__ __forceinline__ u32 f2bf(float f) {
    u32 u = __float_as_uint(f);
    return (u + 0x7fffu + ((u >> 16) & 1u)) >> 16;
}
__device__ __forceinline__ float bf_lo(u32 v) { return __uint_as_float(v << 16); }
__device__ __forceinline__ float bf_hi(u32 v) { return __uint_as_float(v & 0xffff0000u); }

// ================= CSR build =================
__global__ __launch_bounds__(256) void k_hist(const int* __restrict__ dst,
                                              int* __restrict__ deg) {
    int e = blockIdx.x * 256 + threadIdx.x;
    if (e < EE) atomicAdd(&deg[dst[e]], 1);
}

__global__ __launch_bounds__(256) void k_scan1(const int* __restrict__ deg,
                                               int* __restrict__ blk_sums) {
    __shared__ int wsum[4];
    const int lane = threadIdx.x & 63, wid = threadIdx.x >> 6;
    const int base = blockIdx.x * SCAN_CHUNK;
    int s = 0;
    for (int i = threadIdx.x; i < SCAN_CHUNK; i += 256) s += deg[base + i];
    #pragma unroll
    for (int m = 1; m < 64; m <<= 1) s += __shfl_xor(s, m, 64);
    if (lane == 0) wsum[wid] = s;
    __syncthreads();
    if (threadIdx.x == 0)
        blk_sums[blockIdx.x] = wsum[0] + wsum[1] + wsum[2] + wsum[3];
}

__global__ __launch_bounds__(128) void k_scan2(int* __restrict__ blk_sums) {
    __shared__ int lds[128];
    const int tid = threadIdx.x;
    int v = (tid < SCAN_BLOCKS) ? blk_sums[tid] : 0;
    lds[tid] = v;
    __syncthreads();
    for (int off = 1; off < 128; off <<= 1) {
        int t = (tid >= off) ? lds[tid - off] : 0;
        __syncthreads();
        lds[tid] += t;
        __syncthreads();
    }
    if (tid < SCAN_BLOCKS) blk_sums[tid] = (tid == 0) ? 0 : lds[tid - 1];
}

__global__ __launch_bounds__(256) void k_scan3(const int* __restrict__ deg,
                                               const int* __restrict__ blk_off,
                                               int* __restrict__ row_ptr,
                                               int* __restrict__ cursor) {
    __shared__ int wsum[4];
    const int tid = threadIdx.x, lane = tid & 63, wid = tid >> 6;
    const int base = blockIdx.x * SCAN_CHUNK;
    const int g0 = tid * 4;
    int v[4];
    #pragma unroll
    for (int i = 0; i < 4; ++i) {
        int gi = g0 + i;
        v[i] = (gi < SCAN_CHUNK) ? deg[base + gi] : 0;
    }
    const int tsum = v[0] + v[1] + v[2] + v[3];
    int s = tsum;
    #pragma unroll
    for (int off = 1; off < 64; off <<= 1) {
        int t = __shfl_up(s, off, 64);
        if (lane >= off) s += t;
    }
    if (lane == 63) wsum[wid] = s;
    __syncthreads();
    int woff = 0;
    for (int w = 0; w < wid; ++w) woff += wsum[w];
    int run = blk_off[blockIdx.x] + woff + (s - tsum);
    #pragma unroll
    for (int i = 0; i < 4; ++i) {
        int gi = g0 + i;
        int idx = base + gi;
        if (gi < SCAN_CHUNK) {
            row_ptr[idx] = run;
            cursor[idx] = run;
            run += v[i];
            if (idx == NN - 1) row_ptr[NN] = run;
        }
    }
}

// XCD-windowed scatter: block b -> edge chunk (b>>3), dst window (b&7).
// Window writes concentrate in one XCD's L2 -> write-combined before eviction.
__global__ __launch_bounds__(256) void k_scatter(const int* __restrict__ src,
                                                 const int* __restrict__ dst,
                                                 int* __restrict__ cursor,
                                                 int* __restrict__ col_src) {
    const int w = blockIdx.x & (SC_NW - 1);
    const int chunk = blockIdx.x >> 3;
    const int lo = w * SC_WINW, hi = lo + SC_WINW;
    const int base = chunk * SC_CHUNK;
    const int lim = min(base + SC_CHUNK, EE);
    for (int i = base + threadIdx.x; i < lim; i += 256) {
        int d = dst[i];
        if (d >= lo && d < hi) {
            int p = atomicAdd(&cursor[d], 1);
            col_src[p] = src[i];
        }
    }
}

// ================= GEMM1: h1b(bf16) = feat @ W1 =================
__global__ __launch_bounds__(256) void k_gemm1(const float* __restrict__ feat,
                                               const float* __restrict__ W1,
                                               u32* __restrict__ h1b) {
    __shared__ float a_s[32][33];
    __shared__ float b_s[32][128];
    const int tid = threadIdx.x;
    const int tx = tid & 31, ty = tid >> 5;
    const int n0 = blockIdx.x * 32;
    float4 acc[4] = {};
    for (int kt = 0; kt < IND; kt += 32) {
        {
            int r = tid >> 3, c4 = (tid & 7) * 4;
            const float4 v = *(const float4*)&feat[(size_t)(n0 + r) * IND + kt + c4];
            a_s[r][c4] = v.x; a_s[r][c4 + 1] = v.y; a_s[r][c4 + 2] = v.z; a_s[r][c4 + 3] = v.w;
        }
        {
            int cc = tx * 4;
            #pragma unroll
            for (int rep = 0; rep < 4; ++rep) {
                int kr = ty + rep * 8;
                *(float4*)&b_s[kr][cc] = *(const float4*)&W1[(size_t)(kt + kr) * HF + cc];
            }
        }
        __syncthreads();
        #pragma unroll
        for (int k = 0; k < 32; ++k) {
            float4 b4 = *(float4*)&b_s[k][tx * 4];
            #pragma unroll
            for (int i = 0; i < 4; ++i) {
                float a = a_s[ty * 4 + i][k];
                acc[i].x += a * b4.x; acc[i].y += a * b4.y;
                acc[i].z += a * b4.z; acc[i].w += a * b4.w;
            }
        }
        __syncthreads();
    }
    #pragma unroll
    for (int i = 0; i < 4; ++i) {
        u32 p0 = (f2bf(acc[i].y) << 16) | f2bf(acc[i].x);
        u32 p1 = (f2bf(acc[i].w) << 16) | f2bf(acc[i].z);
        *(uint2*)&h1b[(size_t)(n0 + ty * 4 + i) * 64 + tx * 2] = uint2{p0, p1};
    }
}

// ================= el1/er1 from bf16 h1 =================
__global__ __launch_bounds__(256) void k_elr1(const u32* __restrict__ h1b,
                                              const float* __restrict__ al1,
                                              const float* __restrict__ ar1,
                                              float* __restrict__ el1,
                                              float* __restrict__ er1) {
    const int wid = threadIdx.x >> 6, lane = threadIdx.x & 63;
    const int n = blockIdx.x * 4 + wid;
    const int head = lane >> 4;
    const int fo = (lane & 15) * 2;
    u32 v = h1b[(size_t)n * 64 + lane];
    float hx = bf_lo(v), hy = bf_hi(v);
    float2 al = *(const float2*)&al1[head * F1 + fo];
    float2 ar = *(const float2*)&ar1[head * F1 + fo];
    float pel = hx * al.x + hy * al.y;
    float per = hx * ar.x + hy * ar.y;
    #pragma unroll
    for (int m = 1; m < 16; m <<= 1) {
        pel += __shfl_xor(pel, m, 64);
        per += __shfl_xor(per, m, 64);
    }
    if ((lane & 15) == 0) {
        el1[n * 4 + head] = pel;
        er1[n * 4 + head] = per;
    }
}

// ================= layer-1 aggregation: wave per dst, 4-edge ILP =================
__global__ __launch_bounds__(256) void k_agg1(const int* __restrict__ row_ptr,
                                              const int* __restrict__ col_src,
                                              const u32* __restrict__ h1b,
                                              const float* __restrict__ el1,
                                              const float* __restrict__ er1,
                                              const float* __restrict__ b1,
                                              float* __restrict__ x) {
    const int wid = threadIdx.x >> 6, lane = threadIdx.x & 63;
    const int d = blockIdx.x * 4 + wid;
    if (d >= NN) return;
    const int head = lane >> 4;
    const float erd = er1[d * 4 + head];
    const int beg = row_ptr[d], end = row_ptr[d + 1];
    float accx = 0.f, accy = 0.f, ssum = 0.f;
    int e = beg;
    for (; e + 4 <= end; e += 4) {
        const int s0 = col_src[e],     s1 = col_src[e + 1];
        const int s2 = col_src[e + 2], s3 = col_src[e + 3];
        const u32 v0 = h1b[(size_t)s0 * 64 + lane];
        const u32 v1 = h1b[(size_t)s1 * 64 + lane];
        const u32 v2 = h1b[(size_t)s2 * 64 + lane];
        const u32 v3 = h1b[(size_t)s3 * 64 + lane];
        float c0 = el1[s0 * 4 + head] + erd;
        float c1 = el1[s1 * 4 + head] + erd;
        float c2 = el1[s2 * 4 + head] + erd;
        float c3 = el1[s3 * 4 + head] + erd;
        c0 = c0 > 0.f ? c0 : SLOPE * c0;
        c1 = c1 > 0.f ? c1 : SLOPE * c1;
        c2 = c2 > 0.f ? c2 : SLOPE * c2;
        c3 = c3 > 0.f ? c3 : SLOPE * c3;
        const float e0 = __expf(c0), e1 = __expf(c1);
        const float e2 = __expf(c2), e3 = __expf(c3);
        ssum += (e0 + e1) + (e2 + e3);
        accx += e0 * bf_lo(v0) + e1 * bf_lo(v1) + e2 * bf_lo(v2) + e3 * bf_lo(v3);
        accy += e0 * bf_hi(v0) + e1 * bf_hi(v1) + e2 * bf_hi(v2) + e3 * bf_hi(v3);
    }
    for (; e < end; ++e) {
        const int s = col_src[e];
        const u32 v = h1b[(size_t)s * 64 + lane];
        float c = el1[s * 4 + head] + erd;
        c = c > 0.f ? c : SLOPE * c;
        const float ee = __expf(c);
        ssum += ee;
        accx += ee * bf_lo(v);
        accy += ee * bf_hi(v);
    }
    const float inv = ssum > 0.f ? 1.f / ssum : 0.f;
    const float2 b = *(const float2*)&b1[lane * 2];
    float rx = accx * inv + b.x;
    float ry = accy * inv + b.y;
    rx = rx > 0.f ? rx : expm1f(rx);
    ry = ry > 0.f ? ry : expm1f(ry);
    *(float2*)&x[(size_t)d * HF + lane * 2] = float2{rx, ry};
}

// ================= GEMM2 -> packed bf16 h2b rows [20 pairs | el2 | pad] =================
__global__ __launch_bounds__(256) void k_gemm2(const float* __restrict__ x,
                                               const float* __restrict__ W2,
                                               const float* __restrict__ al2,
                                               const float* __restrict__ ar2,
                                               u32* __restrict__ h2b,
                                               float* __restrict__ er2) {
    __shared__ float w2s[HF * C];
    __shared__ float xs[4][HF];
    __shared__ float al2s[C], ar2s[C];
    const int tid = threadIdx.x;
    for (int i = tid; i < HF * C; i += 256) w2s[i] = W2[i];
    if (tid < C) { al2s[tid] = al2[tid]; ar2s[tid] = ar2[tid]; }
    const int wid = tid >> 6, lane = tid & 63;
    const int n = blockIdx.x * 4 + wid;
    xs[wid][lane] = x[(size_t)n * HF + lane];
    xs[wid][lane + 64] = x[(size_t)n * HF + lane + 64];
    __syncthreads();
    float acc = 0.f;
    if (lane < C) {
        #pragma unroll 4
        for (int k = 0; k < HF; ++k) acc += xs[wid][k] * w2s[k * C + lane];
    }
    float pel = lane < C ? acc * al2s[lane] : 0.f;
    float per = lane < C ? acc * ar2s[lane] : 0.f;
    #pragma unroll
    for (int m = 1; m < 64; m <<= 1) {
        pel += __shfl_xor(pel, m, 64);
        per += __shfl_xor(per, m, 64);
    }
    // pack pairs: lane L<20 holds classes 2L, 2L+1
    float a0 = __shfl(acc, (2 * lane) & 63, 64);
    float a1 = __shfl(acc, (2 * lane + 1) & 63, 64);
    if (lane < 20) {
        h2b[(size_t)n * H2ROW + lane] = (f2bf(a1) << 16) | f2bf(a0);
    }
    if (lane == 20) h2b[(size_t)n * H2ROW + 20] = __float_as_uint(pel);
    if (lane == 0) er2[n] = per;
}

// ================= layer-2 aggregation: wave per dst, 4-edge ILP, packed rows =================
__global__ __launch_bounds__(256) void k_agg2(const int* __restrict__ row_ptr,
                                              const int* __restrict__ col_src,
                                              const u32* __restrict__ h2b,
                                              const float* __restrict__ er2,
                                              const float* __restrict__ b2,
                                              float* __restrict__ out) {
    const int wid = threadIdx.x >> 6, lane = threadIdx.x & 63;
    const int d = blockIdx.x * 4 + wid;
    if (d >= NN) return;
    const float erd = er2[d];
    const int beg = row_ptr[d], end = row_ptr[d + 1];
    const bool act = lane < 20;
    const int ld = act ? lane : 20;   // inactive lanes read the el word (same-line broadcast)
    float acc0 = 0.f, acc1 = 0.f, ssum = 0.f;
    int e = beg;
    for (; e + 4 <= end; e += 4) {
        const int s0 = col_src[e],     s1 = col_src[e + 1];
        const int s2 = col_src[e + 2], s3 = col_src[e + 3];
        const u32 v0 = h2b[(size_t)s0 * H2ROW + ld];
        const u32 v1 = h2b[(size_t)s1 * H2ROW + ld];
        const u32 v2 = h2b[(size_t)s2 * H2ROW + ld];
        const u32 v3 = h2b[(size_t)s3 * H2ROW + ld];
        float c0 = __uint_as_float(h2b[(size_t)s0 * H2ROW + 20]) + erd;
        float c1 = __uint_as_float(h2b[(size_t)s1 * H2ROW + 20]) + erd;
        float c2 = __uint_as_float(h2b[(size_t)s2 * H2ROW + 20]) + erd;
        float c3 = __uint_as_float(h2b[(size_t)s3 * H2ROW + 20]) + erd;
        c0 = c0 > 0.f ? c0 : SLOPE * c0;
        c1 = c1 > 0.f ? c1 : SLOPE * c1;
        c2 = c2 > 0.f ? c2 : SLOPE * c2;
        c3 = c3 > 0.f ? c3 : SLOPE * c3;
        const float e0 = __expf(c0), e1 = __expf(c1);
        const float e2 = __expf(c2), e3 = __expf(c3);
        ssum += (e0 + e1) + (e2 + e3);
        acc0 += e0 * bf_lo(v0) + e1 * bf_lo(v1) + e2 * bf_lo(v2) + e3 * bf_lo(v3);
        acc1 += e0 * bf_hi(v0) + e1 * bf_hi(v1) + e2 * bf_hi(v2) + e3 * bf_hi(v3);
    }
    for (; e < end; ++e) {
        const int s = col_src[e];
        const u32 v = h2b[(size_t)s * H2ROW + ld];
        float c = __uint_as_float(h2b[(size_t)s * H2ROW + 20]) + erd;
        c = c > 0.f ? c : SLOPE * c;
        const float ee = __expf(c);
        ssum += ee;
        acc0 += ee * bf_lo(v);
        acc1 += ee * bf_hi(v);
    }
    if (act) {
        const float inv = ssum > 0.f ? 1.f / ssum : 0.f;
        const float2 b = *(const float2*)&b2[lane * 2];
        float2 r;
        r.x = acc0 * inv + b.x;
        r.y = acc1 * inv + b.y;
        *(float2*)&out[(size_t)d * C + lane * 2] = r;
    }
}

extern "C" void kernel_launch(void* const* d_in, const int* in_sizes, int n_in,
                              void* d_out, int out_size, void* d_ws, size_t ws_size,
                              hipStream_t stream) {
    const float* feat = (const float*)d_in[0];
    const int*   src  = (const int*)d_in[1];
    const int*   dst  = (const int*)d_in[2];
    const float* W1   = (const float*)d_in[3];
    const float* al1  = (const float*)d_in[4];
    const float* ar1  = (const float*)d_in[5];
    const float* b1   = (const float*)d_in[6];
    const float* W2   = (const float*)d_in[7];
    const float* al2  = (const float*)d_in[8];
    const float* ar2  = (const float*)d_in[9];
    const float* b2   = (const float*)d_in[10];
    float* out = (float*)d_out;

    // ---- workspace layout ----
    u32*   h1b = (u32*)d_ws;                        // N*64 u32; reused as h2b (N*24 u32)
    float* x   = (float*)(h1b + (size_t)NN * 64);   // N*128 f32
    float* el1 = x + (size_t)NN * HF;               // N*4
    float* er1 = el1 + (size_t)NN * 4;              // N*4 (er2 reuses: N)
    int* row_ptr = (int*)(er1 + (size_t)NN * 4);    // N+1
    int* cursor  = row_ptr + (NN + 1);              // N
    int* deg     = cursor + NN;                     // N
    int* blk_sums = deg + NN;                       // SCAN_BLOCKS
    int* col_src = blk_sums + SCAN_BLOCKS;          // E
    u32*   h2b = h1b;                               // after agg1 done with h1b
    float* er2 = er1;

    // ---- CSR build (shared by both layers) ----
    hipMemsetAsync(deg, 0, (size_t)NN * sizeof(int), stream);
    k_hist<<<(EE + 255) / 256, 256, 0, stream>>>(dst, deg);
    k_scan1<<<SCAN_BLOCKS, 256, 0, stream>>>(deg, blk_sums);
    k_scan2<<<1, 128, 0, stream>>>(blk_sums);
    k_scan3<<<SCAN_BLOCKS, 256, 0, stream>>>(deg, blk_sums, row_ptr, cursor);
    k_scatter<<<SC_NCHUNK * SC_NW, 256, 0, stream>>>(src, dst, cursor, col_src);

    // ---- layer 1 ----
    k_gemm1<<<NN / 32, 256, 0, stream>>>(feat, W1, h1b);
    k_elr1<<<NN / 4, 256, 0, stream>>>(h1b, al1, ar1, el1, er1);
    k_agg1<<<NN / 4, 256, 0, stream>>>(row_ptr, col_src, h1b, el1, er1, b1, x);

    // ---- layer 2 ----
    k_gemm2<<<NN / 4, 256, 0, stream>>>(x, W2, al2, ar2, h2b, er2);
    k_agg2<<<NN / 4, 256, 0, stream>>>(row_ptr, col_src, h2b, er2, b2, out);
}

// Round 6
// 612.623 us; speedup vs baseline: 3.4868x; 1.1003x over previous
//
#include <hip/hip_runtime.h>
#include <math.h>

typedef unsigned int u32;
typedef __attribute__((ext_vector_type(8))) short bf16x8;
typedef __attribute__((ext_vector_type(4))) float floatx4;

constexpr int NN = 100000;
constexpr int EE = 1600000;
constexpr int IND = 256;
constexpr int F1 = 32;
constexpr int HF = 128;   // H*F1
constexpr int C  = 40;
constexpr float SLOPE = 0.2f;

constexpr int SCAN_BLOCKS = 100;
constexpr int SCAN_CHUNK  = 1000;   // SCAN_BLOCKS * SCAN_CHUNK == NN

constexpr int SC_NW    = 8;                          // scatter windows (== XCDs)
constexpr int SC_WINW  = (NN + SC_NW - 1) / SC_NW;   // 12500 dst nodes / window
constexpr int SC_CHUNK = 8192;                       // edges per chunk
constexpr int SC_NCHUNK = (EE + SC_CHUNK - 1) / SC_CHUNK;  // 196

constexpr int H2ROW = 24;  // u32 per h2b row: 20 bf16x2 pairs + el2 bits + pad

// bf16 helpers (RNE pack, cheap unpack)
__device__ __forceinline__ u32 f2bf(float f) {
    u32 u = __float_as_uint(f);
    return (u + 0x7fffu + ((u >> 16) & 1u)) >> 16;
}
__device__ __forceinline__ float bf_lo(u32 v) { return __uint_as_float(v << 16); }
__device__ __forceinline__ float bf_hi(u32 v) { return __uint_as_float(v & 0xffff0000u); }

// ================= CSR build =================
__global__ __launch_bounds__(256) void k_hist(const int* __restrict__ dst,
                                              int* __restrict__ deg) {
    int e = blockIdx.x * 256 + threadIdx.x;
    if (e < EE) atomicAdd(&deg[dst[e]], 1);
}

__global__ __launch_bounds__(256) void k_scan1(const int* __restrict__ deg,
                                               int* __restrict__ blk_sums) {
    __shared__ int wsum[4];
    const int lane = threadIdx.x & 63, wid = threadIdx.x >> 6;
    const int base = blockIdx.x * SCAN_CHUNK;
    int s = 0;
    for (int i = threadIdx.x; i < SCAN_CHUNK; i += 256) s += deg[base + i];
    #pragma unroll
    for (int m = 1; m < 64; m <<= 1) s += __shfl_xor(s, m, 64);
    if (lane == 0) wsum[wid] = s;
    __syncthreads();
    if (threadIdx.x == 0)
        blk_sums[blockIdx.x] = wsum[0] + wsum[1] + wsum[2] + wsum[3];
}

__global__ __launch_bounds__(128) void k_scan2(int* __restrict__ blk_sums) {
    __shared__ int lds[128];
    const int tid = threadIdx.x;
    int v = (tid < SCAN_BLOCKS) ? blk_sums[tid] : 0;
    lds[tid] = v;
    __syncthreads();
    for (int off = 1; off < 128; off <<= 1) {
        int t = (tid >= off) ? lds[tid - off] : 0;
        __syncthreads();
        lds[tid] += t;
        __syncthreads();
    }
    if (tid < SCAN_BLOCKS) blk_sums[tid] = (tid == 0) ? 0 : lds[tid - 1];
}

__global__ __launch_bounds__(256) void k_scan3(const int* __restrict__ deg,
                                               const int* __restrict__ blk_off,
                                               int* __restrict__ row_ptr,
                                               int* __restrict__ cursor) {
    __shared__ int wsum[4];
    const int tid = threadIdx.x, lane = tid & 63, wid = tid >> 6;
    const int base = blockIdx.x * SCAN_CHUNK;
    const int g0 = tid * 4;
    int v[4];
    #pragma unroll
    for (int i = 0; i < 4; ++i) {
        int gi = g0 + i;
        v[i] = (gi < SCAN_CHUNK) ? deg[base + gi] : 0;
    }
    const int tsum = v[0] + v[1] + v[2] + v[3];
    int s = tsum;
    #pragma unroll
    for (int off = 1; off < 64; off <<= 1) {
        int t = __shfl_up(s, off, 64);
        if (lane >= off) s += t;
    }
    if (lane == 63) wsum[wid] = s;
    __syncthreads();
    int woff = 0;
    for (int w = 0; w < wid; ++w) woff += wsum[w];
    int run = blk_off[blockIdx.x] + woff + (s - tsum);
    #pragma unroll
    for (int i = 0; i < 4; ++i) {
        int gi = g0 + i;
        int idx = base + gi;
        if (gi < SCAN_CHUNK) {
            row_ptr[idx] = run;
            cursor[idx] = run;
            run += v[i];
            if (idx == NN - 1) row_ptr[NN] = run;
        }
    }
}

// XCD-windowed scatter
__global__ __launch_bounds__(256) void k_scatter(const int* __restrict__ src,
                                                 const int* __restrict__ dst,
                                                 int* __restrict__ cursor,
                                                 int* __restrict__ col_src) {
    const int w = blockIdx.x & (SC_NW - 1);
    const int chunk = blockIdx.x >> 3;
    const int lo = w * SC_WINW, hi = lo + SC_WINW;
    const int base = chunk * SC_CHUNK;
    const int lim = min(base + SC_CHUNK, EE);
    for (int i = base + threadIdx.x; i < lim; i += 256) {
        int d = dst[i];
        if (d >= lo && d < hi) {
            int p = atomicAdd(&cursor[d], 1);
            col_src[p] = src[i];
        }
    }
}

// ================= GEMM1 (MFMA bf16): h1b = bf16(feat @ W1) =================
// Block: 128 rows x 128 cols, 4 waves (32 rows x 128 cols each).
// W1^T staged once into 64 KB swizzled LDS (bf16); A-frags straight from
// global with in-register bf16 convert. 16x16x32 MFMA, f32 accumulate.
__global__ __launch_bounds__(256) void k_gemm1(const float* __restrict__ feat,
                                               const float* __restrict__ W1,
                                               u32* __restrict__ h1b) {
    __shared__ u32 w1t[128 * 128];   // row n: 32 octets; octet o stored at (o^(n&7))*4
    const int tid = threadIdx.x;
    // ---- stage W1^T (256x128 f32 -> 128x256 bf16, swizzled) ----
    {
        const int n = tid & 127;
        const int o0 = (tid >> 7) * 16;
        for (int i = 0; i < 16; ++i) {
            const int o = o0 + i;              // k-octet 0..31
            float f0 = W1[(size_t)(o * 8 + 0) * HF + n];
            float f1 = W1[(size_t)(o * 8 + 1) * HF + n];
            float f2 = W1[(size_t)(o * 8 + 2) * HF + n];
            float f3 = W1[(size_t)(o * 8 + 3) * HF + n];
            float f4 = W1[(size_t)(o * 8 + 4) * HF + n];
            float f5 = W1[(size_t)(o * 8 + 5) * HF + n];
            float f6 = W1[(size_t)(o * 8 + 6) * HF + n];
            float f7 = W1[(size_t)(o * 8 + 7) * HF + n];
            uint4 p;
            p.x = (f2bf(f1) << 16) | f2bf(f0);
            p.y = (f2bf(f3) << 16) | f2bf(f2);
            p.z = (f2bf(f5) << 16) | f2bf(f4);
            p.w = (f2bf(f7) << 16) | f2bf(f6);
            *(uint4*)&w1t[n * 128 + ((o ^ (n & 7)) << 2)] = p;
        }
    }
    __syncthreads();

    const int w = tid >> 6, lane = tid & 63;
    const int quad = lane >> 4, l15 = lane & 15;
    const int rbase = blockIdx.x * 128 + w * 32;
    floatx4 acc[2][8] = {};

    for (int ks = 0; ks < 8; ++ks) {
        bf16x8 a[2];
        #pragma unroll
        for (int ri = 0; ri < 2; ++ri) {
            int row = rbase + ri * 16 + l15;
            row = row < NN ? row : NN - 1;
            const size_t base = (size_t)row * IND + ks * 32 + quad * 8;
            const float4 f0 = *(const float4*)&feat[base];
            const float4 f1 = *(const float4*)&feat[base + 4];
            uint4 p;
            p.x = (f2bf(f0.y) << 16) | f2bf(f0.x);
            p.y = (f2bf(f0.w) << 16) | f2bf(f0.z);
            p.z = (f2bf(f1.y) << 16) | f2bf(f1.x);
            p.w = (f2bf(f1.w) << 16) | f2bf(f1.z);
            a[ri] = *(bf16x8*)&p;
        }
        const int g = ks * 4 + quad;
        #pragma unroll
        for (int ci = 0; ci < 8; ++ci) {
            const int n = ci * 16 + l15;
            uint4 bw = *(const uint4*)&w1t[n * 128 + ((g ^ (n & 7)) << 2)];
            bf16x8 b = *(bf16x8*)&bw;
            acc[0][ci] = __builtin_amdgcn_mfma_f32_16x16x32_bf16(a[0], b, acc[0][ci], 0, 0, 0);
            acc[1][ci] = __builtin_amdgcn_mfma_f32_16x16x32_bf16(a[1], b, acc[1][ci], 0, 0, 0);
        }
    }

    // ---- epilogue: C/D layout col=lane&15, row=quad*4+reg; pack bf16 pairs ----
    #pragma unroll
    for (int ri = 0; ri < 2; ++ri) {
        #pragma unroll
        for (int ci = 0; ci < 8; ++ci) {
            #pragma unroll
            for (int r = 0; r < 4; ++r) {
                float v = acc[ri][ci][r];
                float vn = __shfl_xor(v, 1, 64);
                const int row = rbase + ri * 16 + quad * 4 + r;
                if (!(lane & 1) && row < NN) {
                    h1b[(size_t)row * 64 + ci * 8 + (l15 >> 1)] =
                        (f2bf(vn) << 16) | f2bf(v);
                }
            }
        }
    }
}

// ================= el1/er1 from bf16 h1 =================
__global__ __launch_bounds__(256) void k_elr1(const u32* __restrict__ h1b,
                                              const float* __restrict__ al1,
                                              const float* __restrict__ ar1,
                                              float* __restrict__ el1,
                                              float* __restrict__ er1) {
    const int wid = threadIdx.x >> 6, lane = threadIdx.x & 63;
    const int n = blockIdx.x * 4 + wid;
    const int head = lane >> 4;
    const int fo = (lane & 15) * 2;
    u32 v = h1b[(size_t)n * 64 + lane];
    float hx = bf_lo(v), hy = bf_hi(v);
    float2 al = *(const float2*)&al1[head * F1 + fo];
    float2 ar = *(const float2*)&ar1[head * F1 + fo];
    float pel = hx * al.x + hy * al.y;
    float per = hx * ar.x + hy * ar.y;
    #pragma unroll
    for (int m = 1; m < 16; m <<= 1) {
        pel += __shfl_xor(pel, m, 64);
        per += __shfl_xor(per, m, 64);
    }
    if ((lane & 15) == 0) {
        el1[n * 4 + head] = pel;
        er1[n * 4 + head] = per;
    }
}

// ================= layer-1 aggregation: wave per dst, 4-edge ILP =================
__global__ __launch_bounds__(256) void k_agg1(const int* __restrict__ row_ptr,
                                              const int* __restrict__ col_src,
                                              const u32* __restrict__ h1b,
                                              const float* __restrict__ el1,
                                              const float* __restrict__ er1,
                                              const float* __restrict__ b1,
                                              float* __restrict__ x) {
    const int wid = threadIdx.x >> 6, lane = threadIdx.x & 63;
    const int d = blockIdx.x * 4 + wid;
    if (d >= NN) return;
    const int head = lane >> 4;
    const float erd = er1[d * 4 + head];
    const int beg = row_ptr[d], end = row_ptr[d + 1];
    float accx = 0.f, accy = 0.f, ssum = 0.f;
    int e = beg;
    for (; e + 4 <= end; e += 4) {
        const int s0 = col_src[e],     s1 = col_src[e + 1];
        const int s2 = col_src[e + 2], s3 = col_src[e + 3];
        const u32 v0 = h1b[(size_t)s0 * 64 + lane];
        const u32 v1 = h1b[(size_t)s1 * 64 + lane];
        const u32 v2 = h1b[(size_t)s2 * 64 + lane];
        const u32 v3 = h1b[(size_t)s3 * 64 + lane];
        float c0 = el1[s0 * 4 + head] + erd;
        float c1 = el1[s1 * 4 + head] + erd;
        float c2 = el1[s2 * 4 + head] + erd;
        float c3 = el1[s3 * 4 + head] + erd;
        c0 = c0 > 0.f ? c0 : SLOPE * c0;
        c1 = c1 > 0.f ? c1 : SLOPE * c1;
        c2 = c2 > 0.f ? c2 : SLOPE * c2;
        c3 = c3 > 0.f ? c3 : SLOPE * c3;
        const float e0 = __expf(c0), e1 = __expf(c1);
        const float e2 = __expf(c2), e3 = __expf(c3);
        ssum += (e0 + e1) + (e2 + e3);
        accx += e0 * bf_lo(v0) + e1 * bf_lo(v1) + e2 * bf_lo(v2) + e3 * bf_lo(v3);
        accy += e0 * bf_hi(v0) + e1 * bf_hi(v1) + e2 * bf_hi(v2) + e3 * bf_hi(v3);
    }
    for (; e < end; ++e) {
        const int s = col_src[e];
        const u32 v = h1b[(size_t)s * 64 + lane];
        float c = el1[s * 4 + head] + erd;
        c = c > 0.f ? c : SLOPE * c;
        const float ee = __expf(c);
        ssum += ee;
        accx += ee * bf_lo(v);
        accy += ee * bf_hi(v);
    }
    const float inv = ssum > 0.f ? 1.f / ssum : 0.f;
    const float2 b = *(const float2*)&b1[lane * 2];
    float rx = accx * inv + b.x;
    float ry = accy * inv + b.y;
    rx = rx > 0.f ? rx : expm1f(rx);
    ry = ry > 0.f ? ry : expm1f(ry);
    *(float2*)&x[(size_t)d * HF + lane * 2] = float2{rx, ry};
}

// ================= GEMM2 -> packed bf16 h2b rows [20 pairs | el2 | pad] =================
__global__ __launch_bounds__(256) void k_gemm2(const float* __restrict__ x,
                                               const float* __restrict__ W2,
                                               const float* __restrict__ al2,
                                               const float* __restrict__ ar2,
                                               u32* __restrict__ h2b,
                                               float* __restrict__ er2) {
    __shared__ float w2s[HF * C];
    __shared__ float xs[4][HF];
    __shared__ float al2s[C], ar2s[C];
    const int tid = threadIdx.x;
    for (int i = tid; i < HF * C; i += 256) w2s[i] = W2[i];
    if (tid < C) { al2s[tid] = al2[tid]; ar2s[tid] = ar2[tid]; }
    const int wid = tid >> 6, lane = tid & 63;
    const int n = blockIdx.x * 4 + wid;
    xs[wid][lane] = x[(size_t)n * HF + lane];
    xs[wid][lane + 64] = x[(size_t)n * HF + lane + 64];
    __syncthreads();
    float acc = 0.f;
    if (lane < C) {
        #pragma unroll 4
        for (int k = 0; k < HF; ++k) acc += xs[wid][k] * w2s[k * C + lane];
    }
    float pel = lane < C ? acc * al2s[lane] : 0.f;
    float per = lane < C ? acc * ar2s[lane] : 0.f;
    #pragma unroll
    for (int m = 1; m < 64; m <<= 1) {
        pel += __shfl_xor(pel, m, 64);
        per += __shfl_xor(per, m, 64);
    }
    float a0 = __shfl(acc, (2 * lane) & 63, 64);
    float a1 = __shfl(acc, (2 * lane + 1) & 63, 64);
    if (lane < 20) {
        h2b[(size_t)n * H2ROW + lane] = (f2bf(a1) << 16) | f2bf(a0);
    }
    if (lane == 20) h2b[(size_t)n * H2ROW + 20] = __float_as_uint(pel);
    if (lane == 0) er2[n] = per;
}

// ================= layer-2 aggregation: wave per dst, 4-edge ILP, packed rows =================
__global__ __launch_bounds__(256) void k_agg2(const int* __restrict__ row_ptr,
                                              const int* __restrict__ col_src,
                                              const u32* __restrict__ h2b,
                                              const float* __restrict__ er2,
                                              const float* __restrict__ b2,
                                              float* __restrict__ out) {
    const int wid = threadIdx.x >> 6, lane = threadIdx.x & 63;
    const int d = blockIdx.x * 4 + wid;
    if (d >= NN) return;
    const float erd = er2[d];
    const int beg = row_ptr[d], end = row_ptr[d + 1];
    const bool act = lane < 20;
    const int ld = act ? lane : 20;
    float acc0 = 0.f, acc1 = 0.f, ssum = 0.f;
    int e = beg;
    for (; e + 4 <= end; e += 4) {
        const int s0 = col_src[e],     s1 = col_src[e + 1];
        const int s2 = col_src[e + 2], s3 = col_src[e + 3];
        const u32 v0 = h2b[(size_t)s0 * H2ROW + ld];
        const u32 v1 = h2b[(size_t)s1 * H2ROW + ld];
        const u32 v2 = h2b[(size_t)s2 * H2ROW + ld];
        const u32 v3 = h2b[(size_t)s3 * H2ROW + ld];
        float c0 = __uint_as_float(h2b[(size_t)s0 * H2ROW + 20]) + erd;
        float c1 = __uint_as_float(h2b[(size_t)s1 * H2ROW + 20]) + erd;
        float c2 = __uint_as_float(h2b[(size_t)s2 * H2ROW + 20]) + erd;
        float c3 = __uint_as_float(h2b[(size_t)s3 * H2ROW + 20]) + erd;
        c0 = c0 > 0.f ? c0 : SLOPE * c0;
        c1 = c1 > 0.f ? c1 : SLOPE * c1;
        c2 = c2 > 0.f ? c2 : SLOPE * c2;
        c3 = c3 > 0.f ? c3 : SLOPE * c3;
        const float e0 = __expf(c0), e1 = __expf(c1);
        const float e2 = __expf(c2), e3 = __expf(c3);
        ssum += (e0 + e1) + (e2 + e3);
        acc0 += e0 * bf_lo(v0) + e1 * bf_lo(v1) + e2 * bf_lo(v2) + e3 * bf_lo(v3);
        acc1 += e0 * bf_hi(v0) + e1 * bf_hi(v1) + e2 * bf_hi(v2) + e3 * bf_hi(v3);
    }
    for (; e < end; ++e) {
        const int s = col_src[e];
        const u32 v = h2b[(size_t)s * H2ROW + ld];
        float c = __uint_as_float(h2b[(size_t)s * H2ROW + 20]) + erd;
        c = c > 0.f ? c : SLOPE * c;
        const float ee = __expf(c);
        ssum += ee;
        acc0 += ee * bf_lo(v);
        acc1 += ee * bf_hi(v);
    }
    if (act) {
        const float inv = ssum > 0.f ? 1.f / ssum : 0.f;
        const float2 b = *(const float2*)&b2[lane * 2];
        float2 r;
        r.x = acc0 * inv + b.x;
        r.y = acc1 * inv + b.y;
        *(float2*)&out[(size_t)d * C + lane * 2] = r;
    }
}

extern "C" void kernel_launch(void* const* d_in, const int* in_sizes, int n_in,
                              void* d_out, int out_size, void* d_ws, size_t ws_size,
                              hipStream_t stream) {
    const float* feat = (const float*)d_in[0];
    const int*   src  = (const int*)d_in[1];
    const int*   dst  = (const int*)d_in[2];
    const float* W1   = (const float*)d_in[3];
    const float* al1  = (const float*)d_in[4];
    const float* ar1  = (const float*)d_in[5];
    const float* b1   = (const float*)d_in[6];
    const float* W2   = (const float*)d_in[7];
    const float* al2  = (const float*)d_in[8];
    const float* ar2  = (const float*)d_in[9];
    const float* b2   = (const float*)d_in[10];
    float* out = (float*)d_out;

    // ---- workspace layout ----
    u32*   h1b = (u32*)d_ws;                        // N*64 u32; reused as h2b (N*24 u32)
    float* x   = (float*)(h1b + (size_t)NN * 64);   // N*128 f32
    float* el1 = x + (size_t)NN * HF;               // N*4
    float* er1 = el1 + (size_t)NN * 4;              // N*4 (er2 reuses: N)
    int* row_ptr = (int*)(er1 + (size_t)NN * 4);    // N+1
    int* cursor  = row_ptr + (NN + 1);              // N
    int* deg     = cursor + NN;                     // N
    int* blk_sums = deg + NN;                       // SCAN_BLOCKS
    int* col_src = blk_sums + SCAN_BLOCKS;          // E
    u32*   h2b = h1b;                               // after agg1 done with h1b
    float* er2 = er1;

    // ---- CSR build (shared by both layers) ----
    hipMemsetAsync(deg, 0, (size_t)NN * sizeof(int), stream);
    k_hist<<<(EE + 255) / 256, 256, 0, stream>>>(dst, deg);
    k_scan1<<<SCAN_BLOCKS, 256, 0, stream>>>(deg, blk_sums);
    k_scan2<<<1, 128, 0, stream>>>(blk_sums);
    k_scan3<<<SCAN_BLOCKS, 256, 0, stream>>>(deg, blk_sums, row_ptr, cursor);
    k_scatter<<<SC_NCHUNK * SC_NW, 256, 0, stream>>>(src, dst, cursor, col_src);

    // ---- layer 1 ----
    k_gemm1<<<(NN + 127) / 128, 256, 0, stream>>>(feat, W1, h1b);
    k_elr1<<<NN / 4, 256, 0, stream>>>(h1b, al1, ar1, el1, er1);
    k_agg1<<<NN / 4, 256, 0, stream>>>(row_ptr, col_src, h1b, el1, er1, b1, x);

    // ---- layer 2 ----
    k_gemm2<<<NN / 4, 256, 0, stream>>>(x, W2, al2, ar2, h2b, er2);
    k_agg2<<<NN / 4, 256, 0, stream>>>(row_ptr, col_src, h2b, er2, b2, out);
}

// Round 7
// 541.521 us; speedup vs baseline: 3.9446x; 1.1313x over previous
//
#include <hip/hip_runtime.h>
#include <math.h>

typedef unsigned int u32;
typedef __attribute__((ext_vector_type(8))) short bf16x8;
typedef __attribute__((ext_vector_type(4))) float floatx4;

constexpr int NN = 100000;
constexpr int EE = 1600000;
constexpr int IND = 256;
constexpr int F1 = 32;
constexpr int HF = 128;   // H*F1
constexpr int C  = 40;
constexpr float SLOPE = 0.2f;

constexpr int SCAN_BLOCKS = 100;
constexpr int SCAN_CHUNK  = 1000;   // SCAN_BLOCKS * SCAN_CHUNK == NN

constexpr int SC_NW    = 8;
constexpr int SC_WINW  = (NN + SC_NW - 1) / SC_NW;
constexpr int SC_CHUNK = 8192;
constexpr int SC_NCHUNK = (EE + SC_CHUNK - 1) / SC_CHUNK;

constexpr int H2ROW = 24;  // u32 per h2b row: 20 bf16x2 pairs + el2 bits + pad

__device__ __forceinline__ u32 f2bf(float f) {
    u32 u = __float_as_uint(f);
    return (u + 0x7fffu + ((u >> 16) & 1u)) >> 16;
}
__device__ __forceinline__ float bf_lo(u32 v) { return __uint_as_float(v << 16); }
__device__ __forceinline__ float bf_hi(u32 v) { return __uint_as_float(v & 0xffff0000u); }

// ================= CSR build =================
__global__ __launch_bounds__(256) void k_hist(const int* __restrict__ dst,
                                              int* __restrict__ deg) {
    int e = blockIdx.x * 256 + threadIdx.x;
    if (e < EE) atomicAdd(&deg[dst[e]], 1);
}

__global__ __launch_bounds__(256) void k_scan1(const int* __restrict__ deg,
                                               int* __restrict__ blk_sums) {
    __shared__ int wsum[4];
    const int lane = threadIdx.x & 63, wid = threadIdx.x >> 6;
    const int base = blockIdx.x * SCAN_CHUNK;
    int s = 0;
    for (int i = threadIdx.x; i < SCAN_CHUNK; i += 256) s += deg[base + i];
    #pragma unroll
    for (int m = 1; m < 64; m <<= 1) s += __shfl_xor(s, m, 64);
    if (lane == 0) wsum[wid] = s;
    __syncthreads();
    if (threadIdx.x == 0)
        blk_sums[blockIdx.x] = wsum[0] + wsum[1] + wsum[2] + wsum[3];
}

__global__ __launch_bounds__(128) void k_scan2(int* __restrict__ blk_sums) {
    __shared__ int lds[128];
    const int tid = threadIdx.x;
    int v = (tid < SCAN_BLOCKS) ? blk_sums[tid] : 0;
    lds[tid] = v;
    __syncthreads();
    for (int off = 1; off < 128; off <<= 1) {
        int t = (tid >= off) ? lds[tid - off] : 0;
        __syncthreads();
        lds[tid] += t;
        __syncthreads();
    }
    if (tid < SCAN_BLOCKS) blk_sums[tid] = (tid == 0) ? 0 : lds[tid - 1];
}

__global__ __launch_bounds__(256) void k_scan3(const int* __restrict__ deg,
                                               const int* __restrict__ blk_off,
                                               int* __restrict__ row_ptr,
                                               int* __restrict__ cursor) {
    __shared__ int wsum[4];
    const int tid = threadIdx.x, lane = tid & 63, wid = tid >> 6;
    const int base = blockIdx.x * SCAN_CHUNK;
    const int g0 = tid * 4;
    int v[4];
    #pragma unroll
    for (int i = 0; i < 4; ++i) {
        int gi = g0 + i;
        v[i] = (gi < SCAN_CHUNK) ? deg[base + gi] : 0;
    }
    const int tsum = v[0] + v[1] + v[2] + v[3];
    int s = tsum;
    #pragma unroll
    for (int off = 1; off < 64; off <<= 1) {
        int t = __shfl_up(s, off, 64);
        if (lane >= off) s += t;
    }
    if (lane == 63) wsum[wid] = s;
    __syncthreads();
    int woff = 0;
    for (int w = 0; w < wid; ++w) woff += wsum[w];
    int run = blk_off[blockIdx.x] + woff + (s - tsum);
    #pragma unroll
    for (int i = 0; i < 4; ++i) {
        int gi = g0 + i;
        int idx = base + gi;
        if (gi < SCAN_CHUNK) {
            row_ptr[idx] = run;
            cursor[idx] = run;
            run += v[i];
            if (idx == NN - 1) row_ptr[NN] = run;
        }
    }
}

__global__ __launch_bounds__(256) void k_scatter(const int* __restrict__ src,
                                                 const int* __restrict__ dst,
                                                 int* __restrict__ cursor,
                                                 int* __restrict__ col_src) {
    const int w = blockIdx.x & (SC_NW - 1);
    const int chunk = blockIdx.x >> 3;
    const int lo = w * SC_WINW, hi = lo + SC_WINW;
    const int base = chunk * SC_CHUNK;
    const int lim = min(base + SC_CHUNK, EE);
    for (int i = base + threadIdx.x; i < lim; i += 256) {
        int d = dst[i];
        if (d >= lo && d < hi) {
            int p = atomicAdd(&cursor[d], 1);
            col_src[p] = src[i];
        }
    }
}

// ================= GEMM1 (MFMA bf16): h1b = bf16(feat @ W1), + el1/er1 =================
__global__ __launch_bounds__(256) void k_gemm1(const float* __restrict__ feat,
                                               const float* __restrict__ W1,
                                               const float* __restrict__ al1,
                                               const float* __restrict__ ar1,
                                               u32* __restrict__ h1b,
                                               float* __restrict__ el1,
                                               float* __restrict__ er1) {
    __shared__ u32 w1t[128 * 128];
    const int tid = threadIdx.x;
    {
        const int n = tid & 127;
        const int o0 = (tid >> 7) * 16;
        for (int i = 0; i < 16; ++i) {
            const int o = o0 + i;
            float f0 = W1[(size_t)(o * 8 + 0) * HF + n];
            float f1 = W1[(size_t)(o * 8 + 1) * HF + n];
            float f2 = W1[(size_t)(o * 8 + 2) * HF + n];
            float f3 = W1[(size_t)(o * 8 + 3) * HF + n];
            float f4 = W1[(size_t)(o * 8 + 4) * HF + n];
            float f5 = W1[(size_t)(o * 8 + 5) * HF + n];
            float f6 = W1[(size_t)(o * 8 + 6) * HF + n];
            float f7 = W1[(size_t)(o * 8 + 7) * HF + n];
            uint4 p;
            p.x = (f2bf(f1) << 16) | f2bf(f0);
            p.y = (f2bf(f3) << 16) | f2bf(f2);
            p.z = (f2bf(f5) << 16) | f2bf(f4);
            p.w = (f2bf(f7) << 16) | f2bf(f6);
            *(uint4*)&w1t[n * 128 + ((o ^ (n & 7)) << 2)] = p;
        }
    }
    __syncthreads();

    const int w = tid >> 6, lane = tid & 63;
    const int quad = lane >> 4, l15 = lane & 15;
    const int rbase = blockIdx.x * 128 + w * 32;

    // attention vectors for epilogue
    float alv[4][2], arv[4][2];
    #pragma unroll
    for (int h = 0; h < 4; ++h) {
        alv[h][0] = al1[h * F1 + l15];
        alv[h][1] = al1[h * F1 + 16 + l15];
        arv[h][0] = ar1[h * F1 + l15];
        arv[h][1] = ar1[h * F1 + 16 + l15];
    }

    floatx4 acc[2][8] = {};
    for (int ks = 0; ks < 8; ++ks) {
        bf16x8 a[2];
        #pragma unroll
        for (int ri = 0; ri < 2; ++ri) {
            int row = rbase + ri * 16 + l15;
            row = row < NN ? row : NN - 1;
            const size_t base = (size_t)row * IND + ks * 32 + quad * 8;
            const float4 f0 = *(const float4*)&feat[base];
            const float4 f1 = *(const float4*)&feat[base + 4];
            uint4 p;
            p.x = (f2bf(f0.y) << 16) | f2bf(f0.x);
            p.y = (f2bf(f0.w) << 16) | f2bf(f0.z);
            p.z = (f2bf(f1.y) << 16) | f2bf(f1.x);
            p.w = (f2bf(f1.w) << 16) | f2bf(f1.z);
            a[ri] = *(bf16x8*)&p;
        }
        const int g = ks * 4 + quad;
        #pragma unroll
        for (int ci = 0; ci < 8; ++ci) {
            const int n = ci * 16 + l15;
            uint4 bw = *(const uint4*)&w1t[n * 128 + ((g ^ (n & 7)) << 2)];
            bf16x8 b = *(bf16x8*)&bw;
            acc[0][ci] = __builtin_amdgcn_mfma_f32_16x16x32_bf16(a[0], b, acc[0][ci], 0, 0, 0);
            acc[1][ci] = __builtin_amdgcn_mfma_f32_16x16x32_bf16(a[1], b, acc[1][ci], 0, 0, 0);
        }
    }

    // ---- epilogue: pack h1b + compute el1/er1 from f32 acc ----
    #pragma unroll
    for (int ri = 0; ri < 2; ++ri) {
        #pragma unroll
        for (int r = 0; r < 4; ++r) {
            const int row = rbase + ri * 16 + quad * 4 + r;
            const bool rok = row < NN;
            #pragma unroll
            for (int h = 0; h < 4; ++h) {
                float pe = acc[ri][2 * h][r] * alv[h][0] + acc[ri][2 * h + 1][r] * alv[h][1];
                float pr = acc[ri][2 * h][r] * arv[h][0] + acc[ri][2 * h + 1][r] * arv[h][1];
                #pragma unroll
                for (int m = 1; m < 16; m <<= 1) {
                    pe += __shfl_xor(pe, m, 64);
                    pr += __shfl_xor(pr, m, 64);
                }
                if (l15 == 0 && rok) {
                    el1[row * 4 + h] = pe;
                    er1[row * 4 + h] = pr;
                }
            }
            #pragma unroll
            for (int ci = 0; ci < 8; ++ci) {
                float v = acc[ri][ci][r];
                float vn = __shfl_xor(v, 1, 64);
                if (!(lane & 1) && rok) {
                    h1b[(size_t)row * 64 + ci * 8 + (l15 >> 1)] =
                        (f2bf(vn) << 16) | f2bf(v);
                }
            }
        }
    }
}

// ================= layer-1 aggregation: wave per dst, 4-edge ILP, bf16 x out =================
__global__ __launch_bounds__(256) void k_agg1(const int* __restrict__ row_ptr,
                                              const int* __restrict__ col_src,
                                              const u32* __restrict__ h1b,
                                              const float* __restrict__ el1,
                                              const float* __restrict__ er1,
                                              const float* __restrict__ b1,
                                              u32* __restrict__ x_b) {
    const int wid = threadIdx.x >> 6, lane = threadIdx.x & 63;
    const int d = blockIdx.x * 4 + wid;
    if (d >= NN) return;
    const int head = lane >> 4;
    const float erd = er1[d * 4 + head];
    const int beg = row_ptr[d], end = row_ptr[d + 1];
    float accx = 0.f, accy = 0.f, ssum = 0.f;
    int e = beg;
    for (; e + 4 <= end; e += 4) {
        const int s0 = col_src[e],     s1 = col_src[e + 1];
        const int s2 = col_src[e + 2], s3 = col_src[e + 3];
        const u32 v0 = h1b[(size_t)s0 * 64 + lane];
        const u32 v1 = h1b[(size_t)s1 * 64 + lane];
        const u32 v2 = h1b[(size_t)s2 * 64 + lane];
        const u32 v3 = h1b[(size_t)s3 * 64 + lane];
        float c0 = el1[s0 * 4 + head] + erd;
        float c1 = el1[s1 * 4 + head] + erd;
        float c2 = el1[s2 * 4 + head] + erd;
        float c3 = el1[s3 * 4 + head] + erd;
        c0 = c0 > 0.f ? c0 : SLOPE * c0;
        c1 = c1 > 0.f ? c1 : SLOPE * c1;
        c2 = c2 > 0.f ? c2 : SLOPE * c2;
        c3 = c3 > 0.f ? c3 : SLOPE * c3;
        const float e0 = __expf(c0), e1 = __expf(c1);
        const float e2 = __expf(c2), e3 = __expf(c3);
        ssum += (e0 + e1) + (e2 + e3);
        accx += e0 * bf_lo(v0) + e1 * bf_lo(v1) + e2 * bf_lo(v2) + e3 * bf_lo(v3);
        accy += e0 * bf_hi(v0) + e1 * bf_hi(v1) + e2 * bf_hi(v2) + e3 * bf_hi(v3);
    }
    for (; e < end; ++e) {
        const int s = col_src[e];
        const u32 v = h1b[(size_t)s * 64 + lane];
        float c = el1[s * 4 + head] + erd;
        c = c > 0.f ? c : SLOPE * c;
        const float ee = __expf(c);
        ssum += ee;
        accx += ee * bf_lo(v);
        accy += ee * bf_hi(v);
    }
    const float inv = ssum > 0.f ? 1.f / ssum : 0.f;
    const float2 b = *(const float2*)&b1[lane * 2];
    float rx = accx * inv + b.x;
    float ry = accy * inv + b.y;
    rx = rx > 0.f ? rx : expm1f(rx);
    ry = ry > 0.f ? ry : expm1f(ry);
    x_b[(size_t)d * 64 + lane] = (f2bf(ry) << 16) | f2bf(rx);
}

// ================= GEMM2 (MFMA bf16): h2b = pack(x @ [W2|waux_l|waux_r]) =================
// 48 padded cols: 0-39 = classes, 40 = el2 (x·(W2@al2)), 41 = er2, 42-47 zero.
__global__ __launch_bounds__(256) void k_gemm2(const u32* __restrict__ x_b,
                                               const float* __restrict__ W2,
                                               const float* __restrict__ al2,
                                               const float* __restrict__ ar2,
                                               u32* __restrict__ h2b,
                                               float* __restrict__ er2) {
    __shared__ u32 w2t[48 * 64];   // row n: 16 k-octets, octet g at ((g^(n&7))<<2)
    const int tid = threadIdx.x;
    {
        const int o = tid & 15;
        const int n0 = tid >> 4;
        for (int n = n0; n < 48; n += 16) {
            float f[8];
            #pragma unroll
            for (int j = 0; j < 8; ++j) {
                const int k = o * 8 + j;
                float v;
                if (n < C) v = W2[(size_t)k * C + n];
                else if (n == 40) {
                    v = 0.f;
                    for (int c = 0; c < C; ++c) v += W2[(size_t)k * C + c] * al2[c];
                } else if (n == 41) {
                    v = 0.f;
                    for (int c = 0; c < C; ++c) v += W2[(size_t)k * C + c] * ar2[c];
                } else v = 0.f;
                f[j] = v;
            }
            uint4 p;
            p.x = (f2bf(f[1]) << 16) | f2bf(f[0]);
            p.y = (f2bf(f[3]) << 16) | f2bf(f[2]);
            p.z = (f2bf(f[5]) << 16) | f2bf(f[4]);
            p.w = (f2bf(f[7]) << 16) | f2bf(f[6]);
            *(uint4*)&w2t[n * 64 + ((o ^ (n & 7)) << 2)] = p;
        }
    }
    __syncthreads();

    const int w = tid >> 6, lane = tid & 63;
    const int quad = lane >> 4, l15 = lane & 15;
    const int rbase = blockIdx.x * 128 + w * 32;
    floatx4 acc[2][3] = {};

    #pragma unroll
    for (int ks = 0; ks < 4; ++ks) {
        bf16x8 a[2];
        #pragma unroll
        for (int ri = 0; ri < 2; ++ri) {
            int row = rbase + ri * 16 + l15;
            row = row < NN ? row : NN - 1;
            uint4 ax = *(const uint4*)&x_b[(size_t)row * 64 + ks * 16 + quad * 4];
            a[ri] = *(bf16x8*)&ax;
        }
        const int g = ks * 4 + quad;
        #pragma unroll
        for (int ci = 0; ci < 3; ++ci) {
            const int n = ci * 16 + l15;
            uint4 bw = *(const uint4*)&w2t[n * 64 + ((g ^ (n & 7)) << 2)];
            bf16x8 b = *(bf16x8*)&bw;
            acc[0][ci] = __builtin_amdgcn_mfma_f32_16x16x32_bf16(a[0], b, acc[0][ci], 0, 0, 0);
            acc[1][ci] = __builtin_amdgcn_mfma_f32_16x16x32_bf16(a[1], b, acc[1][ci], 0, 0, 0);
        }
    }

    // epilogue: pack h2b rows; col40 -> el2 word, col41 -> er2 array
    #pragma unroll
    for (int ri = 0; ri < 2; ++ri) {
        #pragma unroll
        for (int r = 0; r < 4; ++r) {
            const int row = rbase + ri * 16 + quad * 4 + r;
            const bool rok = row < NN;
            #pragma unroll
            for (int ci = 0; ci < 3; ++ci) {
                float v = acc[ri][ci][r];
                float vn = __shfl_xor(v, 1, 64);
                if (rok) {
                    if (ci < 2) {
                        if (!(lane & 1))
                            h2b[(size_t)row * H2ROW + ci * 8 + (l15 >> 1)] =
                                (f2bf(vn) << 16) | f2bf(v);
                    } else {
                        if (!(lane & 1) && l15 < 8)
                            h2b[(size_t)row * H2ROW + 16 + (l15 >> 1)] =
                                (f2bf(vn) << 16) | f2bf(v);
                        else if (l15 == 8)
                            h2b[(size_t)row * H2ROW + 20] = __float_as_uint(v);
                        else if (l15 == 9)
                            er2[row] = v;
                    }
                }
            }
        }
    }
}

// ================= layer-2 aggregation =================
__global__ __launch_bounds__(256) void k_agg2(const int* __restrict__ row_ptr,
                                              const int* __restrict__ col_src,
                                              const u32* __restrict__ h2b,
                                              const float* __restrict__ er2,
                                              const float* __restrict__ b2,
                                              float* __restrict__ out) {
    const int wid = threadIdx.x >> 6, lane = threadIdx.x & 63;
    const int d = blockIdx.x * 4 + wid;
    if (d >= NN) return;
    const float erd = er2[d];
    const int beg = row_ptr[d], end = row_ptr[d + 1];
    const bool act = lane < 20;
    const int ld = act ? lane : 20;
    float acc0 = 0.f, acc1 = 0.f, ssum = 0.f;
    int e = beg;
    for (; e + 4 <= end; e += 4) {
        const int s0 = col_src[e],     s1 = col_src[e + 1];
        const int s2 = col_src[e + 2], s3 = col_src[e + 3];
        const u32 v0 = h2b[(size_t)s0 * H2ROW + ld];
        const u32 v1 = h2b[(size_t)s1 * H2ROW + ld];
        const u32 v2 = h2b[(size_t)s2 * H2ROW + ld];
        const u32 v3 = h2b[(size_t)s3 * H2ROW + ld];
        float c0 = __uint_as_float(h2b[(size_t)s0 * H2ROW + 20]) + erd;
        float c1 = __uint_as_float(h2b[(size_t)s1 * H2ROW + 20]) + erd;
        float c2 = __uint_as_float(h2b[(size_t)s2 * H2ROW + 20]) + erd;
        float c3 = __uint_as_float(h2b[(size_t)s3 * H2ROW + 20]) + erd;
        c0 = c0 > 0.f ? c0 : SLOPE * c0;
        c1 = c1 > 0.f ? c1 : SLOPE * c1;
        c2 = c2 > 0.f ? c2 : SLOPE * c2;
        c3 = c3 > 0.f ? c3 : SLOPE * c3;
        const float e0 = __expf(c0), e1 = __expf(c1);
        const float e2 = __expf(c2), e3 = __expf(c3);
        ssum += (e0 + e1) + (e2 + e3);
        acc0 += e0 * bf_lo(v0) + e1 * bf_lo(v1) + e2 * bf_lo(v2) + e3 * bf_lo(v3);
        acc1 += e0 * bf_hi(v0) + e1 * bf_hi(v1) + e2 * bf_hi(v2) + e3 * bf_hi(v3);
    }
    for (; e < end; ++e) {
        const int s = col_src[e];
        const u32 v = h2b[(size_t)s * H2ROW + ld];
        float c = __uint_as_float(h2b[(size_t)s * H2ROW + 20]) + erd;
        c = c > 0.f ? c : SLOPE * c;
        const float ee = __expf(c);
        ssum += ee;
        acc0 += ee * bf_lo(v);
        acc1 += ee * bf_hi(v);
    }
    if (act) {
        const float inv = ssum > 0.f ? 1.f / ssum : 0.f;
        const float2 b = *(const float2*)&b2[lane * 2];
        float2 r;
        r.x = acc0 * inv + b.x;
        r.y = acc1 * inv + b.y;
        *(float2*)&out[(size_t)d * C + lane * 2] = r;
    }
}

extern "C" void kernel_launch(void* const* d_in, const int* in_sizes, int n_in,
                              void* d_out, int out_size, void* d_ws, size_t ws_size,
                              hipStream_t stream) {
    const float* feat = (const float*)d_in[0];
    const int*   src  = (const int*)d_in[1];
    const int*   dst  = (const int*)d_in[2];
    const float* W1   = (const float*)d_in[3];
    const float* al1  = (const float*)d_in[4];
    const float* ar1  = (const float*)d_in[5];
    const float* b1   = (const float*)d_in[6];
    const float* W2   = (const float*)d_in[7];
    const float* al2  = (const float*)d_in[8];
    const float* ar2  = (const float*)d_in[9];
    const float* b2   = (const float*)d_in[10];
    float* out = (float*)d_out;

    // ---- workspace layout ----
    u32*   h1b = (u32*)d_ws;                        // N*64 u32; reused as h2b (N*24)
    u32*   x_b = h1b + (size_t)NN * 64;             // N*64 u32 (bf16 x)
    float* el1 = (float*)(x_b + (size_t)NN * 64);   // N*4
    float* er1 = el1 + (size_t)NN * 4;              // N*4 (er2 reuses: N)
    int* row_ptr = (int*)(er1 + (size_t)NN * 4);    // N+1
    int* cursor  = row_ptr + (NN + 1);              // N
    int* deg     = cursor + NN;                     // N
    int* blk_sums = deg + NN;                       // SCAN_BLOCKS
    int* col_src = blk_sums + SCAN_BLOCKS;          // E
    u32*   h2b = h1b;
    float* er2 = er1;

    // ---- CSR build ----
    hipMemsetAsync(deg, 0, (size_t)NN * sizeof(int), stream);
    k_hist<<<(EE + 255) / 256, 256, 0, stream>>>(dst, deg);
    k_scan1<<<SCAN_BLOCKS, 256, 0, stream>>>(deg, blk_sums);
    k_scan2<<<1, 128, 0, stream>>>(blk_sums);
    k_scan3<<<SCAN_BLOCKS, 256, 0, stream>>>(deg, blk_sums, row_ptr, cursor);
    k_scatter<<<SC_NCHUNK * SC_NW, 256, 0, stream>>>(src, dst, cursor, col_src);

    // ---- layer 1 ----
    k_gemm1<<<(NN + 127) / 128, 256, 0, stream>>>(feat, W1, al1, ar1, h1b, el1, er1);
    k_agg1<<<NN / 4, 256, 0, stream>>>(row_ptr, col_src, h1b, el1, er1, b1, x_b);

    // ---- layer 2 ----
    k_gemm2<<<(NN + 127) / 128, 256, 0, stream>>>(x_b, W2, al2, ar2, h2b, er2);
    k_agg2<<<NN / 4, 256, 0, stream>>>(row_ptr, col_src, h2b, er2, b2, out);
}